// Round 1
// baseline (699.705 us; speedup 1.0000x reference)
//
#include <hip/hip_runtime.h>
#include <math.h>

#define NN 4096
#define DD 512
#define K_TOP 10
#define K_HALF 5

// ---------------- helpers ----------------

__device__ inline float block_reduce_sum_f(float v, float* red) {
    int tid = threadIdx.x;
    red[tid] = v;
    __syncthreads();
    for (int st = 128; st > 0; st >>= 1) {
        if (tid < st) red[tid] += red[tid + st];
        __syncthreads();
    }
    float r = red[0];
    __syncthreads();
    return r;
}

__device__ inline double block_reduce_sum_d(double v, double* red) {
    int tid = threadIdx.x;
    red[tid] = v;
    __syncthreads();
    for (int st = 128; st > 0; st >>= 1) {
        if (tid < st) red[tid] += red[tid + st];
        __syncthreads();
    }
    double r = red[0];
    __syncthreads();
    return r;
}

// ---------------- K0: row norms, normalize t ----------------

__global__ __launch_bounds__(256) void prep_kernel(
    const float* __restrict__ s, const float* __restrict__ t,
    float* __restrict__ tn, float* __restrict__ sn2, float* __restrict__ tn2)
{
    int row = blockIdx.x;
    int tid = threadIdx.x;
    const float* srow = s + (size_t)row * DD;
    const float* trow = t + (size_t)row * DD;
    float s0 = srow[tid], s1 = srow[tid + 256];
    float t0 = trow[tid], t1 = trow[tid + 256];
    __shared__ float red[256];
    float ssum = block_reduce_sum_f(s0 * s0 + s1 * s1, red);
    float tsum = block_reduce_sum_f(t0 * t0 + t1 * t1, red);
    float nrm = fmaxf(sqrtf(tsum), 1e-12f);
    float u0 = t0 / nrm, u1 = t1 / nrm;
    tn[(size_t)row * DD + tid] = u0;
    tn[(size_t)row * DD + tid + 256] = u1;
    float usum = block_reduce_sum_f(u0 * u0 + u1 * u1, red);
    if (tid == 0) {
        sn2[row] = ssum;
        tn2[row] = usum;
    }
}

// ---------------- K1: tiled f32 Gram -> S_dist raw (MODE 0) or W_P (MODE 1) ----------------

template <int MODE>
__global__ __launch_bounds__(256) void gram_kernel(
    const float* __restrict__ X, const float* __restrict__ xsq, float* __restrict__ out)
{
    __shared__ float As[32][68];
    __shared__ float Bs[32][68];
    int i0 = blockIdx.y * 64, j0 = blockIdx.x * 64;
    int tid = threadIdx.x;
    int lr = tid >> 3;          // 0..31
    int lc = (tid & 7) << 2;    // 0,4,..,28
    int ty = tid >> 4, tx = tid & 15;
    float acc[4][4] = {{0.f}};

    for (int k0 = 0; k0 < DD; k0 += 32) {
        float4 a0 = *(const float4*)(X + (size_t)(i0 + lr) * DD + k0 + lc);
        float4 a1 = *(const float4*)(X + (size_t)(i0 + lr + 32) * DD + k0 + lc);
        float4 b0 = *(const float4*)(X + (size_t)(j0 + lr) * DD + k0 + lc);
        float4 b1 = *(const float4*)(X + (size_t)(j0 + lr + 32) * DD + k0 + lc);
        As[lc + 0][lr] = a0.x; As[lc + 1][lr] = a0.y; As[lc + 2][lr] = a0.z; As[lc + 3][lr] = a0.w;
        As[lc + 0][lr + 32] = a1.x; As[lc + 1][lr + 32] = a1.y; As[lc + 2][lr + 32] = a1.z; As[lc + 3][lr + 32] = a1.w;
        Bs[lc + 0][lr] = b0.x; Bs[lc + 1][lr] = b0.y; Bs[lc + 2][lr] = b0.z; Bs[lc + 3][lr] = b0.w;
        Bs[lc + 0][lr + 32] = b1.x; Bs[lc + 1][lr + 32] = b1.y; Bs[lc + 2][lr + 32] = b1.z; Bs[lc + 3][lr + 32] = b1.w;
        __syncthreads();
#pragma unroll
        for (int kk = 0; kk < 32; ++kk) {
            float4 av = *(const float4*)(&As[kk][ty << 2]);
            float4 bv = *(const float4*)(&Bs[kk][tx << 2]);
            float am[4] = {av.x, av.y, av.z, av.w};
            float bm[4] = {bv.x, bv.y, bv.z, bv.w};
#pragma unroll
            for (int m = 0; m < 4; ++m)
#pragma unroll
                for (int n = 0; n < 4; ++n)
                    acc[m][n] = fmaf(am[m], bm[n], acc[m][n]);
        }
        __syncthreads();
    }

    float xi[4], xj[4];
#pragma unroll
    for (int m = 0; m < 4; ++m) xi[m] = xsq[i0 + (ty << 2) + m];
#pragma unroll
    for (int n = 0; n < 4; ++n) xj[n] = xsq[j0 + (tx << 2) + n];
#pragma unroll
    for (int m = 0; m < 4; ++m) {
        float4 o;
        float* op = &o.x;
#pragma unroll
        for (int n = 0; n < 4; ++n) {
            float d2 = xi[m] + xj[n] - 2.0f * acc[m][n];
            d2 = fmaxf(d2, 0.0f);
            op[n] = (MODE == 0) ? sqrtf(d2) : expf(-d2);
        }
        *(float4*)(out + (size_t)(i0 + (ty << 2) + m) * NN + j0 + (tx << 2)) = o;
    }
}

// ---------------- K2: row mean of Sraw -> inverse mean ----------------

__global__ __launch_bounds__(256) void rowmean_kernel(
    const float* __restrict__ Sraw, float* __restrict__ invm)
{
    int row = blockIdx.x, tid = threadIdx.x;
    const float4* p = (const float4*)(Sraw + (size_t)row * NN);
    float acc = 0.f;
    for (int j = tid; j < NN / 4; j += 256) {
        float4 v = p[j];
        acc += v.x + v.y + v.z + v.w;
    }
    __shared__ float red[256];
    float total = block_reduce_sum_f(acc, red);
    if (tid == 0) {
        float mean = total / (float)NN;
        invm[row] = 1.0f / mean;
    }
}

// ---------------- K3: per-row stable top-10 of W_P_copy ----------------

__global__ __launch_bounds__(256) void topk_kernel(
    const float* __restrict__ WP, const int* __restrict__ idx, int* __restrict__ topk)
{
    __shared__ float vals[NN];
    __shared__ float rv[256];
    __shared__ int ri[256];
    int row = blockIdx.x, tid = threadIdx.x;
    int myidx = idx[row];
    const float* wrow = WP + (size_t)row * NN;
    for (int j = tid; j < NN; j += 256)
        vals[j] = (idx[j] == myidx) ? 1.0f : wrow[j];
    __syncthreads();
    for (int k = 0; k < K_TOP; ++k) {
        float bv = -2.0f;
        int bi = NN;
        for (int j = tid; j < NN; j += 256) {
            float v = vals[j];
            if (v > bv || (v == bv && j < bi)) { bv = v; bi = j; }
        }
        rv[tid] = bv; ri[tid] = bi;
        __syncthreads();
        for (int st = 128; st > 0; st >>= 1) {
            if (tid < st) {
                float v2 = rv[tid + st];
                int i2 = ri[tid + st];
                if (v2 > rv[tid] || (v2 == rv[tid] && i2 < ri[tid])) { rv[tid] = v2; ri[tid] = i2; }
            }
            __syncthreads();
        }
        if (tid == 0) {
            topk[row * K_TOP + k] = ri[0];
            vals[ri[0]] = -2.0f;
        }
        __syncthreads();
    }
}

// ---------------- K4: mutual-NN lists (V) ----------------

__global__ __launch_bounds__(256) void mutual_kernel(
    const int* __restrict__ topk, int* __restrict__ vnbr, int* __restrict__ vcnt)
{
    int i = blockIdx.x * 256 + threadIdx.x;
    if (i >= NN) return;
    int mine[K_TOP];
#pragma unroll
    for (int a = 0; a < K_TOP; ++a) mine[a] = topk[i * K_TOP + a];
    int cnt = 0;
    int out[K_TOP];
#pragma unroll
    for (int a = 0; a < K_TOP; ++a) {
        int j = mine[a];
        bool found = false;
#pragma unroll
        for (int b = 0; b < K_TOP; ++b) found |= (topk[j * K_TOP + b] == i);
        if (found) out[cnt++] = j;
    }
    vcnt[i] = cnt;
    for (int a = 0; a < cnt; ++a) vnbr[i * K_TOP + a] = out[a];
    for (int a = cnt; a < K_TOP; ++a) vnbr[i * K_TOP + a] = -1;
}

// ---------------- K5: W_C_tilda values (co/deg) at V-neighbor slots ----------------

__global__ __launch_bounds__(256) void wct_kernel(
    const int* __restrict__ vnbr, const int* __restrict__ vcnt, float* __restrict__ wct)
{
    int i = blockIdx.x * 256 + threadIdx.x;
    if (i >= NN) return;
    int cnt = vcnt[i];
    int mine[K_TOP];
#pragma unroll
    for (int a = 0; a < K_TOP; ++a) mine[a] = vnbr[i * K_TOP + a];
    float invdeg = 1.0f / fmaxf((float)cnt, 1.0f);
    for (int a = 0; a < K_TOP; ++a) {
        if (a < cnt) {
            int j = mine[a];
            int cj = vcnt[j];
            int co = 0;
            for (int b = 0; b < cj; ++b) {
                int v = vnbr[j * K_TOP + b];
#pragma unroll
                for (int c = 0; c < K_TOP; ++c)
                    co += (c < cnt && mine[c] == v) ? 1 : 0;
            }
            wct[i * K_TOP + a] = (float)co * invdeg;
        } else {
            wct[i * K_TOP + a] = 0.0f;
        }
    }
}

// ---------------- K6: sparse W_C correction ----------------

__global__ __launch_bounds__(256) void corr_kernel(
    const int* __restrict__ topk, const int* __restrict__ vnbr, const int* __restrict__ vcnt,
    const float* __restrict__ wct, const float* __restrict__ Sraw,
    const float* __restrict__ invm, double* __restrict__ partial)
{
    int r = blockIdx.x * 256 + threadIdx.x;
    double acc = 0.0;
    if (r < NN) {
        float im_r = invm[r];
        for (int a = 0; a < K_HALF; ++a) {
            int k = topk[r * K_TOP + a];
            int ck = vcnt[k];
            for (int b = 0; b < ck; ++b) {
                int c = vnbr[k * K_TOP + b];
                if (c == r) continue;
                float w = wct[k * K_TOP + b];
                float sr = Sraw[(size_t)r * NN + c];
                float s1 = sr * im_r;
                float r1 = fmaxf(1.0f - s1, 0.0f);
                float g1 = s1 * s1 - r1 * r1;
                float s2 = sr * invm[c];
                float r2 = fmaxf(1.0f - s2, 0.0f);
                float g2 = s2 * s2 - r2 * r2;
                acc += (double)(w * (g1 + g2)) * (1.0 / 20.0);
            }
        }
    }
    __shared__ double red[256];
    double total = block_reduce_sum_d(acc, red);
    if (threadIdx.x == 0) partial[blockIdx.x] = total;
}

// ---------------- K7: dense loss part ----------------

__global__ __launch_bounds__(256) void dense_kernel(
    const float* __restrict__ Sraw, const float* __restrict__ WP,
    const float* __restrict__ invm, double* __restrict__ partial)
{
    int row = blockIdx.x, tid = threadIdx.x;
    const float4* S4 = (const float4*)(Sraw + (size_t)row * NN);
    const float4* W4 = (const float4*)(WP + (size_t)row * NN);
    float im = invm[row];
    double acc = 0.0;
    for (int j4 = tid; j4 < NN / 4; j4 += 256) {
        float4 sv = S4[j4];
        float4 wv = W4[j4];
        float ss[4] = {sv.x, sv.y, sv.z, sv.w};
        float ww[4] = {wv.x, wv.y, wv.z, wv.w};
#pragma unroll
        for (int c = 0; c < 4; ++c) {
            int j = j4 * 4 + c;
            if (j == row) continue;
            float sc = ss[c] * im;
            float rr = fmaxf(1.0f - sc, 0.0f);
            float term = rr * rr + 0.5f * ww[c] * (sc * sc - rr * rr);
            acc += (double)term;
        }
    }
    __shared__ double red[256];
    double total = block_reduce_sum_d(acc, red);
    if (tid == 0) partial[row] = total;
}

// ---------------- K8: final reduce ----------------

__global__ __launch_bounds__(256) void final_kernel(
    const double* __restrict__ pDense, const double* __restrict__ pCorr, float* __restrict__ out)
{
    int tid = threadIdx.x;
    double a = 0.0;
    for (int j = tid; j < NN; j += 256) a += pDense[j];
    if (tid < 16) a += pCorr[tid];
    __shared__ double red[256];
    double total = block_reduce_sum_d(a, red);
    if (tid == 0) out[0] = (float)(total / ((double)NN * (double)(NN - 1)));
}

// ---------------- launcher ----------------

extern "C" void kernel_launch(void* const* d_in, const int* in_sizes, int n_in,
                              void* d_out, int out_size, void* d_ws, size_t ws_size,
                              hipStream_t stream)
{
    const float* s = (const float*)d_in[0];
    const float* t = (const float*)d_in[1];
    const int* idx = (const int*)d_in[2];
    float* out = (float*)d_out;

    char* base = (char*)d_ws;
    size_t off = 0;
    auto alloc = [&](size_t bytes) -> void* {
        void* p = base + off;
        off = (off + bytes + 511) & ~(size_t)511;
        return p;
    };

    float* Sraw = (float*)alloc((size_t)NN * NN * 4);
    float* WP   = (float*)alloc((size_t)NN * NN * 4);
    float* tn   = (float*)alloc((size_t)NN * DD * 4);
    float* sn2  = (float*)alloc(NN * 4);
    float* tn2  = (float*)alloc(NN * 4);
    float* invm = (float*)alloc(NN * 4);
    int* topk   = (int*)alloc(NN * K_TOP * 4);
    int* vnbr   = (int*)alloc(NN * K_TOP * 4);
    int* vcnt   = (int*)alloc(NN * 4);
    float* wct  = (float*)alloc(NN * K_TOP * 4);
    double* pDense = (double*)alloc(NN * 8);
    double* pCorr  = (double*)alloc(16 * 8);
    (void)ws_size;

    prep_kernel<<<NN, 256, 0, stream>>>(s, t, tn, sn2, tn2);

    dim3 ggrid(NN / 64, NN / 64);
    gram_kernel<0><<<ggrid, 256, 0, stream>>>(s, sn2, Sraw);
    gram_kernel<1><<<ggrid, 256, 0, stream>>>(tn, tn2, WP);

    rowmean_kernel<<<NN, 256, 0, stream>>>(Sraw, invm);
    topk_kernel<<<NN, 256, 0, stream>>>(WP, idx, topk);
    mutual_kernel<<<NN / 256, 256, 0, stream>>>(topk, vnbr, vcnt);
    wct_kernel<<<NN / 256, 256, 0, stream>>>(vnbr, vcnt, wct);
    corr_kernel<<<NN / 256, 256, 0, stream>>>(topk, vnbr, vcnt, wct, Sraw, invm, pCorr);
    dense_kernel<<<NN, 256, 0, stream>>>(Sraw, WP, invm, pDense);
    final_kernel<<<1, 256, 0, stream>>>(pDense, pCorr, out);
}

// Round 2
// 350.546 us; speedup vs baseline: 1.9960x; 1.9960x over previous
//
#include <hip/hip_runtime.h>
#include <math.h>

#define NN 4096
#define DD 512
#define K_TOP 10
#define K_HALF 5

typedef short bf16x8 __attribute__((ext_vector_type(8)));
typedef float f32x4 __attribute__((ext_vector_type(4)));

// ---------------- helpers ----------------

__device__ inline float block_reduce_sum_f(float v, float* red) {
    int tid = threadIdx.x;
    red[tid] = v;
    __syncthreads();
    for (int st = 128; st > 0; st >>= 1) {
        if (tid < st) red[tid] += red[tid + st];
        __syncthreads();
    }
    float r = red[0];
    __syncthreads();
    return r;
}

__device__ inline double block_reduce_sum_d(double v, double* red) {
    int tid = threadIdx.x;
    red[tid] = v;
    __syncthreads();
    for (int st = 128; st > 0; st >>= 1) {
        if (tid < st) red[tid] += red[tid + st];
        __syncthreads();
    }
    double r = red[0];
    __syncthreads();
    return r;
}

__device__ inline unsigned short f2bf(float x) {
    unsigned u = __float_as_uint(x);
    unsigned r = (u + 0x7fffu + ((u >> 16) & 1u)) >> 16;
    return (unsigned short)r;
}

__device__ inline float bf2f(unsigned short b) {
    unsigned u = ((unsigned)b) << 16;
    return __uint_as_float(u);
}

__device__ inline void gload_lds16(const void* g, void* l) {
    __builtin_amdgcn_global_load_lds((const __attribute__((address_space(1))) void*)g,
                                     (__attribute__((address_space(3))) void*)l, 16, 0, 0);
}

// ---------------- K0: norms + s hi/lo split ----------------

__global__ __launch_bounds__(256) void prep_kernel(
    const float* __restrict__ s, const float* __restrict__ t,
    unsigned short* __restrict__ hi, unsigned short* __restrict__ lo,
    float* __restrict__ sn2, float* __restrict__ tn2)
{
    int row = blockIdx.x;
    int tid = threadIdx.x;
    const float* srow = s + (size_t)row * DD;
    const float* trow = t + (size_t)row * DD;
    float s0 = srow[tid], s1 = srow[tid + 256];
    float t0 = trow[tid], t1 = trow[tid + 256];
    __shared__ float red[256];
    float ssum = block_reduce_sum_f(s0 * s0 + s1 * s1, red);
    float tsum = block_reduce_sum_f(t0 * t0 + t1 * t1, red);
    float nrm = fmaxf(sqrtf(tsum), 1e-12f);
    float u0 = t0 / nrm, u1 = t1 / nrm;
    float usum = block_reduce_sum_f(u0 * u0 + u1 * u1, red);
    // split s into hi/lo bf16
    unsigned short h0 = f2bf(s0), h1 = f2bf(s1);
    float l0 = s0 - bf2f(h0), l1 = s1 - bf2f(h1);
    hi[(size_t)row * DD + tid] = h0;
    hi[(size_t)row * DD + tid + 256] = h1;
    lo[(size_t)row * DD + tid] = f2bf(l0);
    lo[(size_t)row * DD + tid + 256] = f2bf(l1);
    if (tid == 0) {
        sn2[row] = ssum;
        tn2[row] = usum;
    }
}

// ---------------- K0b: tn hi/lo split (reuses split buffers) ----------------

__global__ __launch_bounds__(256) void prep2_kernel(
    const float* __restrict__ t,
    unsigned short* __restrict__ hi, unsigned short* __restrict__ lo)
{
    int row = blockIdx.x;
    int tid = threadIdx.x;
    const float* trow = t + (size_t)row * DD;
    float t0 = trow[tid], t1 = trow[tid + 256];
    __shared__ float red[256];
    float tsum = block_reduce_sum_f(t0 * t0 + t1 * t1, red);
    float nrm = fmaxf(sqrtf(tsum), 1e-12f);
    float u0 = t0 / nrm, u1 = t1 / nrm;
    unsigned short h0 = f2bf(u0), h1 = f2bf(u1);
    float l0 = u0 - bf2f(h0), l1 = u1 - bf2f(h1);
    hi[(size_t)row * DD + tid] = h0;
    hi[(size_t)row * DD + tid + 256] = h1;
    lo[(size_t)row * DD + tid] = f2bf(l0);
    lo[(size_t)row * DD + tid + 256] = f2bf(l1);
}

// ---------------- K1: MFMA Gram (3-pass bf16 split) ----------------
// MODE 0: out = sqrt(max(d2,0))   MODE 1: out = exp(-max(d2,0))

#define BM 128
#define BK 32

template <int MODE>
__global__ __launch_bounds__(256) void gram_mfma_kernel(
    const unsigned short* __restrict__ Xhi, const unsigned short* __restrict__ Xlo,
    const float* __restrict__ xsq, float* __restrict__ out)
{
    __shared__ unsigned short lsAh[BM * BK];
    __shared__ unsigned short lsAl[BM * BK];
    __shared__ unsigned short lsBh[BM * BK];
    __shared__ unsigned short lsBl[BM * BK];

    int i0 = blockIdx.y * BM, j0 = blockIdx.x * BM;
    int t = threadIdx.x;
    int wave = t >> 6, lane = t & 63;
    int wr = wave >> 1, wc = wave & 1;

    f32x4 acc[4][4] = {};

    int srow = t >> 2;
    int scol = (t & 3) * 8;

    for (int k0 = 0; k0 < DD; k0 += BK) {
#pragma unroll
        for (int p = 0; p < 2; ++p) {
            size_t ga = (size_t)(i0 + p * 64 + srow) * DD + k0 + scol;
            size_t gb = (size_t)(j0 + p * 64 + srow) * DD + k0 + scol;
            int lofs = p * 2048 + t * 8;
            gload_lds16(Xhi + ga, &lsAh[lofs]);
            gload_lds16(Xlo + ga, &lsAl[lofs]);
            gload_lds16(Xhi + gb, &lsBh[lofs]);
            gload_lds16(Xlo + gb, &lsBl[lofs]);
        }
        __syncthreads();

        int fr = lane & 15, kg = lane >> 4;
        bf16x8 ah[4], al[4], bh[4], bl[4];
#pragma unroll
        for (int m = 0; m < 4; ++m) {
            int row = wr * 64 + m * 16 + fr;
            ah[m] = *(const bf16x8*)&lsAh[row * BK + kg * 8];
            al[m] = *(const bf16x8*)&lsAl[row * BK + kg * 8];
        }
#pragma unroll
        for (int n = 0; n < 4; ++n) {
            int row = wc * 64 + n * 16 + fr;
            bh[n] = *(const bf16x8*)&lsBh[row * BK + kg * 8];
            bl[n] = *(const bf16x8*)&lsBl[row * BK + kg * 8];
        }
#pragma unroll
        for (int m = 0; m < 4; ++m)
#pragma unroll
            for (int n = 0; n < 4; ++n) {
                acc[m][n] = __builtin_amdgcn_mfma_f32_16x16x32_bf16(ah[m], bh[n], acc[m][n], 0, 0, 0);
                acc[m][n] = __builtin_amdgcn_mfma_f32_16x16x32_bf16(ah[m], bl[n], acc[m][n], 0, 0, 0);
                acc[m][n] = __builtin_amdgcn_mfma_f32_16x16x32_bf16(al[m], bh[n], acc[m][n], 0, 0, 0);
            }
        __syncthreads();
    }

    // epilogue: C/D layout col = lane&15, row = (lane>>4)*4 + reg
    int fr = lane & 15, fq = lane >> 4;
    float xj[4];
#pragma unroll
    for (int n = 0; n < 4; ++n) xj[n] = xsq[j0 + wc * 64 + n * 16 + fr];
#pragma unroll
    for (int m = 0; m < 4; ++m) {
#pragma unroll
        for (int r = 0; r < 4; ++r) {
            int i = i0 + wr * 64 + m * 16 + fq * 4 + r;
            float xi = xsq[i];
#pragma unroll
            for (int n = 0; n < 4; ++n) {
                int j = j0 + wc * 64 + n * 16 + fr;
                float d2 = xi + xj[n] - 2.0f * acc[m][n][r];
                d2 = fmaxf(d2, 0.0f);
                float v = (MODE == 0) ? sqrtf(d2) : expf(-d2);
                out[(size_t)i * NN + j] = v;
            }
        }
    }
}

// ---------------- K2: row mean of Sraw -> inverse mean ----------------

__global__ __launch_bounds__(256) void rowmean_kernel(
    const float* __restrict__ Sraw, float* __restrict__ invm)
{
    int row = blockIdx.x, tid = threadIdx.x;
    const float4* p = (const float4*)(Sraw + (size_t)row * NN);
    float acc = 0.f;
    for (int j = tid; j < NN / 4; j += 256) {
        float4 v = p[j];
        acc += v.x + v.y + v.z + v.w;
    }
    __shared__ float red[256];
    float total = block_reduce_sum_f(acc, red);
    if (tid == 0) {
        float mean = total / (float)NN;
        invm[row] = 1.0f / mean;
    }
}

// ---------------- K3: per-row stable top-10 of W_P_copy ----------------

__global__ __launch_bounds__(256) void topk_kernel(
    const float* __restrict__ WP, const int* __restrict__ idx, int* __restrict__ topk)
{
    __shared__ float vals[NN];
    __shared__ float rv[256];
    __shared__ int ri[256];
    int row = blockIdx.x, tid = threadIdx.x;
    int myidx = idx[row];
    const float* wrow = WP + (size_t)row * NN;
    for (int j = tid; j < NN; j += 256)
        vals[j] = (idx[j] == myidx) ? 1.0f : wrow[j];
    __syncthreads();
    for (int k = 0; k < K_TOP; ++k) {
        float bv = -2.0f;
        int bi = NN;
        for (int j = tid; j < NN; j += 256) {
            float v = vals[j];
            if (v > bv || (v == bv && j < bi)) { bv = v; bi = j; }
        }
        rv[tid] = bv; ri[tid] = bi;
        __syncthreads();
        for (int st = 128; st > 0; st >>= 1) {
            if (tid < st) {
                float v2 = rv[tid + st];
                int i2 = ri[tid + st];
                if (v2 > rv[tid] || (v2 == rv[tid] && i2 < ri[tid])) { rv[tid] = v2; ri[tid] = i2; }
            }
            __syncthreads();
        }
        if (tid == 0) {
            topk[row * K_TOP + k] = ri[0];
            vals[ri[0]] = -2.0f;
        }
        __syncthreads();
    }
}

// ---------------- K4: mutual-NN lists (V) ----------------

__global__ __launch_bounds__(256) void mutual_kernel(
    const int* __restrict__ topk, int* __restrict__ vnbr, int* __restrict__ vcnt)
{
    int i = blockIdx.x * 256 + threadIdx.x;
    if (i >= NN) return;
    int mine[K_TOP];
#pragma unroll
    for (int a = 0; a < K_TOP; ++a) mine[a] = topk[i * K_TOP + a];
    int cnt = 0;
    int out[K_TOP];
#pragma unroll
    for (int a = 0; a < K_TOP; ++a) {
        int j = mine[a];
        bool found = false;
#pragma unroll
        for (int b = 0; b < K_TOP; ++b) found |= (topk[j * K_TOP + b] == i);
        if (found) out[cnt++] = j;
    }
    vcnt[i] = cnt;
    for (int a = 0; a < cnt; ++a) vnbr[i * K_TOP + a] = out[a];
    for (int a = cnt; a < K_TOP; ++a) vnbr[i * K_TOP + a] = -1;
}

// ---------------- K5: W_C_tilda values (co/deg) ----------------

__global__ __launch_bounds__(256) void wct_kernel(
    const int* __restrict__ vnbr, const int* __restrict__ vcnt, float* __restrict__ wct)
{
    int i = blockIdx.x * 256 + threadIdx.x;
    if (i >= NN) return;
    int cnt = vcnt[i];
    int mine[K_TOP];
#pragma unroll
    for (int a = 0; a < K_TOP; ++a) mine[a] = vnbr[i * K_TOP + a];
    float invdeg = 1.0f / fmaxf((float)cnt, 1.0f);
    for (int a = 0; a < K_TOP; ++a) {
        if (a < cnt) {
            int j = mine[a];
            int cj = vcnt[j];
            int co = 0;
            for (int b = 0; b < cj; ++b) {
                int v = vnbr[j * K_TOP + b];
#pragma unroll
            for (int c = 0; c < K_TOP; ++c)
                    co += (c < cnt && mine[c] == v) ? 1 : 0;
            }
            wct[i * K_TOP + a] = (float)co * invdeg;
        } else {
            wct[i * K_TOP + a] = 0.0f;
        }
    }
}

// ---------------- K6: sparse W_C correction ----------------

__global__ __launch_bounds__(256) void corr_kernel(
    const int* __restrict__ topk, const int* __restrict__ vnbr, const int* __restrict__ vcnt,
    const float* __restrict__ wct, const float* __restrict__ Sraw,
    const float* __restrict__ invm, double* __restrict__ partial)
{
    int r = blockIdx.x * 256 + threadIdx.x;
    double acc = 0.0;
    if (r < NN) {
        float im_r = invm[r];
        for (int a = 0; a < K_HALF; ++a) {
            int k = topk[r * K_TOP + a];
            int ck = vcnt[k];
            for (int b = 0; b < ck; ++b) {
                int c = vnbr[k * K_TOP + b];
                if (c == r) continue;
                float w = wct[k * K_TOP + b];
                float sr = Sraw[(size_t)r * NN + c];
                float s1 = sr * im_r;
                float r1 = fmaxf(1.0f - s1, 0.0f);
                float g1 = s1 * s1 - r1 * r1;
                float s2 = sr * invm[c];
                float r2 = fmaxf(1.0f - s2, 0.0f);
                float g2 = s2 * s2 - r2 * r2;
                acc += (double)(w * (g1 + g2)) * (1.0 / 20.0);
            }
        }
    }
    __shared__ double red[256];
    double total = block_reduce_sum_d(acc, red);
    if (threadIdx.x == 0) partial[blockIdx.x] = total;
}

// ---------------- K7: dense loss part ----------------

__global__ __launch_bounds__(256) void dense_kernel(
    const float* __restrict__ Sraw, const float* __restrict__ WP,
    const float* __restrict__ invm, double* __restrict__ partial)
{
    int row = blockIdx.x, tid = threadIdx.x;
    const float4* S4 = (const float4*)(Sraw + (size_t)row * NN);
    const float4* W4 = (const float4*)(WP + (size_t)row * NN);
    float im = invm[row];
    double acc = 0.0;
    for (int j4 = tid; j4 < NN / 4; j4 += 256) {
        float4 sv = S4[j4];
        float4 wv = W4[j4];
        float ss[4] = {sv.x, sv.y, sv.z, sv.w};
        float ww[4] = {wv.x, wv.y, wv.z, wv.w};
#pragma unroll
        for (int c = 0; c < 4; ++c) {
            int j = j4 * 4 + c;
            if (j == row) continue;
            float sc = ss[c] * im;
            float rr = fmaxf(1.0f - sc, 0.0f);
            float term = rr * rr + 0.5f * ww[c] * (sc * sc - rr * rr);
            acc += (double)term;
        }
    }
    __shared__ double red[256];
    double total = block_reduce_sum_d(acc, red);
    if (tid == 0) partial[row] = total;
}

// ---------------- K8: final reduce ----------------

__global__ __launch_bounds__(256) void final_kernel(
    const double* __restrict__ pDense, const double* __restrict__ pCorr, float* __restrict__ out)
{
    int tid = threadIdx.x;
    double a = 0.0;
    for (int j = tid; j < NN; j += 256) a += pDense[j];
    if (tid < 16) a += pCorr[tid];
    __shared__ double red[256];
    double total = block_reduce_sum_d(a, red);
    if (tid == 0) out[0] = (float)(total / ((double)NN * (double)(NN - 1)));
}

// ---------------- launcher ----------------

extern "C" void kernel_launch(void* const* d_in, const int* in_sizes, int n_in,
                              void* d_out, int out_size, void* d_ws, size_t ws_size,
                              hipStream_t stream)
{
    const float* s = (const float*)d_in[0];
    const float* t = (const float*)d_in[1];
    const int* idx = (const int*)d_in[2];
    float* out = (float*)d_out;

    char* base = (char*)d_ws;
    size_t off = 0;
    auto alloc = [&](size_t bytes) -> void* {
        void* p = base + off;
        off = (off + bytes + 511) & ~(size_t)511;
        return p;
    };

    float* Sraw = (float*)alloc((size_t)NN * NN * 4);
    float* WP   = (float*)alloc((size_t)NN * NN * 4);
    unsigned short* hi = (unsigned short*)alloc((size_t)NN * DD * 2);
    unsigned short* lo = (unsigned short*)alloc((size_t)NN * DD * 2);
    float* sn2  = (float*)alloc(NN * 4);
    float* tn2  = (float*)alloc(NN * 4);
    float* invm = (float*)alloc(NN * 4);
    int* topk   = (int*)alloc(NN * K_TOP * 4);
    int* vnbr   = (int*)alloc(NN * K_TOP * 4);
    int* vcnt   = (int*)alloc(NN * 4);
    float* wct  = (float*)alloc(NN * K_TOP * 4);
    double* pDense = (double*)alloc(NN * 8);
    double* pCorr  = (double*)alloc(16 * 8);
    (void)ws_size;

    dim3 ggrid(NN / BM, NN / BM);

    // s splits + norms
    prep_kernel<<<NN, 256, 0, stream>>>(s, t, hi, lo, sn2, tn2);
    // S Gram (uses s splits)
    gram_mfma_kernel<0><<<ggrid, 256, 0, stream>>>(hi, lo, sn2, Sraw);
    // tn splits (overwrite split buffers)
    prep2_kernel<<<NN, 256, 0, stream>>>(t, hi, lo);
    // T Gram -> W_P
    gram_mfma_kernel<1><<<ggrid, 256, 0, stream>>>(hi, lo, tn2, WP);

    rowmean_kernel<<<NN, 256, 0, stream>>>(Sraw, invm);
    topk_kernel<<<NN, 256, 0, stream>>>(WP, idx, topk);
    mutual_kernel<<<NN / 256, 256, 0, stream>>>(topk, vnbr, vcnt);
    wct_kernel<<<NN / 256, 256, 0, stream>>>(vnbr, vcnt, wct);
    corr_kernel<<<NN / 256, 256, 0, stream>>>(topk, vnbr, vcnt, wct, Sraw, invm, pCorr);
    dense_kernel<<<NN, 256, 0, stream>>>(Sraw, WP, invm, pDense);
    final_kernel<<<1, 256, 0, stream>>>(pDense, pCorr, out);
}

// Round 3
// 299.210 us; speedup vs baseline: 2.3385x; 1.1716x over previous
//
#include <hip/hip_runtime.h>
#include <math.h>

#define NN 4096
#define DD 512
#define K_TOP 10
#define K_HALF 5

typedef short bf16x8 __attribute__((ext_vector_type(8)));
typedef float f32x4 __attribute__((ext_vector_type(4)));

// ---------------- helpers ----------------

__device__ inline float block_reduce_sum_f(float v, float* red) {
    int tid = threadIdx.x;
    red[tid] = v;
    __syncthreads();
    for (int st = 128; st > 0; st >>= 1) {
        if (tid < st) red[tid] += red[tid + st];
        __syncthreads();
    }
    float r = red[0];
    __syncthreads();
    return r;
}

__device__ inline double block_reduce_sum_d(double v, double* red) {
    int tid = threadIdx.x;
    red[tid] = v;
    __syncthreads();
    for (int st = 128; st > 0; st >>= 1) {
        if (tid < st) red[tid] += red[tid + st];
        __syncthreads();
    }
    double r = red[0];
    __syncthreads();
    return r;
}

__device__ inline unsigned short f2bf(float x) {
    unsigned u = __float_as_uint(x);
    unsigned r = (u + 0x7fffu + ((u >> 16) & 1u)) >> 16;
    return (unsigned short)r;
}

__device__ inline float bf2f(unsigned short b) {
    unsigned u = ((unsigned)b) << 16;
    return __uint_as_float(u);
}

__device__ inline void gload_lds16(const void* g, void* l) {
    __builtin_amdgcn_global_load_lds((const __attribute__((address_space(1))) void*)g,
                                     (__attribute__((address_space(3))) void*)l, 16, 0, 0);
}

// ---------------- K0: norms + s hi/lo split ----------------

__global__ __launch_bounds__(256) void prep_kernel(
    const float* __restrict__ s, const float* __restrict__ t,
    unsigned short* __restrict__ hi, unsigned short* __restrict__ lo,
    float* __restrict__ sn2, float* __restrict__ tn2)
{
    int row = blockIdx.x;
    int tid = threadIdx.x;
    const float* srow = s + (size_t)row * DD;
    const float* trow = t + (size_t)row * DD;
    float s0 = srow[tid], s1 = srow[tid + 256];
    float t0 = trow[tid], t1 = trow[tid + 256];
    __shared__ float red[256];
    float ssum = block_reduce_sum_f(s0 * s0 + s1 * s1, red);
    float tsum = block_reduce_sum_f(t0 * t0 + t1 * t1, red);
    float nrm = fmaxf(sqrtf(tsum), 1e-12f);
    float u0 = t0 / nrm, u1 = t1 / nrm;
    float usum = block_reduce_sum_f(u0 * u0 + u1 * u1, red);
    unsigned short h0 = f2bf(s0), h1 = f2bf(s1);
    float l0 = s0 - bf2f(h0), l1 = s1 - bf2f(h1);
    hi[(size_t)row * DD + tid] = h0;
    hi[(size_t)row * DD + tid + 256] = h1;
    lo[(size_t)row * DD + tid] = f2bf(l0);
    lo[(size_t)row * DD + tid + 256] = f2bf(l1);
    if (tid == 0) {
        sn2[row] = ssum;
        tn2[row] = usum;
    }
}

// ---------------- K0b: tn hi/lo split (reuses split buffers) ----------------

__global__ __launch_bounds__(256) void prep2_kernel(
    const float* __restrict__ t,
    unsigned short* __restrict__ hi, unsigned short* __restrict__ lo)
{
    int row = blockIdx.x;
    int tid = threadIdx.x;
    const float* trow = t + (size_t)row * DD;
    float t0 = trow[tid], t1 = trow[tid + 256];
    __shared__ float red[256];
    float tsum = block_reduce_sum_f(t0 * t0 + t1 * t1, red);
    float nrm = fmaxf(sqrtf(tsum), 1e-12f);
    float u0 = t0 / nrm, u1 = t1 / nrm;
    unsigned short h0 = f2bf(u0), h1 = f2bf(u1);
    float l0 = u0 - bf2f(h0), l1 = u1 - bf2f(h1);
    hi[(size_t)row * DD + tid] = h0;
    hi[(size_t)row * DD + tid + 256] = h1;
    lo[(size_t)row * DD + tid] = f2bf(l0);
    lo[(size_t)row * DD + tid + 256] = f2bf(l1);
}

// ---------------- K1: MFMA Gram (3-pass bf16 split) ----------------

#define BM 128
#define BK 32

template <int MODE>
__global__ __launch_bounds__(256) void gram_mfma_kernel(
    const unsigned short* __restrict__ Xhi, const unsigned short* __restrict__ Xlo,
    const float* __restrict__ xsq, float* __restrict__ out)
{
    __shared__ unsigned short lsAh[BM * BK];
    __shared__ unsigned short lsAl[BM * BK];
    __shared__ unsigned short lsBh[BM * BK];
    __shared__ unsigned short lsBl[BM * BK];

    int i0 = blockIdx.y * BM, j0 = blockIdx.x * BM;
    int t = threadIdx.x;
    int wave = t >> 6, lane = t & 63;
    int wr = wave >> 1, wc = wave & 1;

    f32x4 acc[4][4] = {};

    int srow = t >> 2;
    int scol = (t & 3) * 8;

    for (int k0 = 0; k0 < DD; k0 += BK) {
#pragma unroll
        for (int p = 0; p < 2; ++p) {
            size_t ga = (size_t)(i0 + p * 64 + srow) * DD + k0 + scol;
            size_t gb = (size_t)(j0 + p * 64 + srow) * DD + k0 + scol;
            int lofs = p * 2048 + t * 8;
            gload_lds16(Xhi + ga, &lsAh[lofs]);
            gload_lds16(Xlo + ga, &lsAl[lofs]);
            gload_lds16(Xhi + gb, &lsBh[lofs]);
            gload_lds16(Xlo + gb, &lsBl[lofs]);
        }
        __syncthreads();

        int fr = lane & 15, kg = lane >> 4;
        bf16x8 ah[4], al[4], bh[4], bl[4];
#pragma unroll
        for (int m = 0; m < 4; ++m) {
            int row = wr * 64 + m * 16 + fr;
            ah[m] = *(const bf16x8*)&lsAh[row * BK + kg * 8];
            al[m] = *(const bf16x8*)&lsAl[row * BK + kg * 8];
        }
#pragma unroll
        for (int n = 0; n < 4; ++n) {
            int row = wc * 64 + n * 16 + fr;
            bh[n] = *(const bf16x8*)&lsBh[row * BK + kg * 8];
            bl[n] = *(const bf16x8*)&lsBl[row * BK + kg * 8];
        }
#pragma unroll
        for (int m = 0; m < 4; ++m)
#pragma unroll
            for (int n = 0; n < 4; ++n) {
                acc[m][n] = __builtin_amdgcn_mfma_f32_16x16x32_bf16(ah[m], bh[n], acc[m][n], 0, 0, 0);
                acc[m][n] = __builtin_amdgcn_mfma_f32_16x16x32_bf16(ah[m], bl[n], acc[m][n], 0, 0, 0);
                acc[m][n] = __builtin_amdgcn_mfma_f32_16x16x32_bf16(al[m], bh[n], acc[m][n], 0, 0, 0);
            }
        __syncthreads();
    }

    int fr = lane & 15, fq = lane >> 4;
    float xj[4];
#pragma unroll
    for (int n = 0; n < 4; ++n) xj[n] = xsq[j0 + wc * 64 + n * 16 + fr];
#pragma unroll
    for (int m = 0; m < 4; ++m) {
#pragma unroll
        for (int r = 0; r < 4; ++r) {
            int i = i0 + wr * 64 + m * 16 + fq * 4 + r;
            float xi = xsq[i];
#pragma unroll
            for (int n = 0; n < 4; ++n) {
                int j = j0 + wc * 64 + n * 16 + fr;
                float d2 = xi + xj[n] - 2.0f * acc[m][n][r];
                d2 = fmaxf(d2, 0.0f);
                float v = (MODE == 0) ? sqrtf(d2) : expf(-d2);
                out[(size_t)i * NN + j] = v;
            }
        }
    }
}

// ---------------- K2: row mean of Sraw -> inverse mean ----------------

__global__ __launch_bounds__(256) void rowmean_kernel(
    const float* __restrict__ Sraw, float* __restrict__ invm)
{
    int row = blockIdx.x, tid = threadIdx.x;
    const float4* p = (const float4*)(Sraw + (size_t)row * NN);
    float acc = 0.f;
    for (int j = tid; j < NN / 4; j += 256) {
        float4 v = p[j];
        acc += v.x + v.y + v.z + v.w;
    }
    __shared__ float red[256];
    float total = block_reduce_sum_f(acc, red);
    if (tid == 0) {
        float mean = total / (float)NN;
        invm[row] = 1.0f / mean;
    }
}

// ---------------- K3: per-row stable top-10 (single pass + tree merge) ----------------

__global__ __launch_bounds__(256) void topk_kernel(
    const float* __restrict__ WP, const int* __restrict__ idx, int* __restrict__ topk)
{
    __shared__ float mv[256 * K_TOP];
    __shared__ int   mi[256 * K_TOP];
    int row = blockIdx.x, tid = threadIdx.x;
    int myidx = idx[row];
    const float4* w4 = (const float4*)(WP + (size_t)row * NN);
    const int4* i4 = (const int4*)idx;

    float v[K_TOP];
    int id[K_TOP];
#pragma unroll
    for (int p = 0; p < K_TOP; ++p) { v[p] = -2.0f; id[p] = 0x7fffffff; }

    // per-thread scan: elements j = 4*(tid + 256*q) + c, index-ascending
#pragma unroll
    for (int q = 0; q < 4; ++q) {
        int j4 = tid + 256 * q;
        float4 wv = w4[j4];
        int4 iv = i4[j4];
        float e[4] = {wv.x, wv.y, wv.z, wv.w};
        int ii[4] = {iv.x, iv.y, iv.z, iv.w};
#pragma unroll
        for (int c = 0; c < 4; ++c) {
            int j = j4 * 4 + c;
            float nv = (ii[c] == myidx) ? 1.0f : e[c];
            // stable shift-insertion (ties keep earlier index above)
#pragma unroll
            for (int p = K_TOP - 1; p >= 1; --p) {
                if (nv > v[p - 1]) { v[p] = v[p - 1]; id[p] = id[p - 1]; }
                else if (nv > v[p]) { v[p] = nv; id[p] = j; }
            }
            if (nv > v[0]) { v[0] = nv; id[0] = j; }
        }
    }

#pragma unroll
    for (int p = 0; p < K_TOP; ++p) { mv[tid * K_TOP + p] = v[p]; mi[tid * K_TOP + p] = id[p]; }
    __syncthreads();

    for (int stride = 128; stride >= 1; stride >>= 1) {
        if (tid < stride) {
            int a = tid * K_TOP, b = (tid + stride) * K_TOP;
            float ov[K_TOP];
            int oi[K_TOP];
            int pa = 0, pb = 0;
#pragma unroll
            for (int p = 0; p < K_TOP; ++p) {
                float va = mv[a + pa], vb = mv[b + pb];
                int ia = mi[a + pa], ib = mi[b + pb];
                bool ta = (va > vb) || (va == vb && ia < ib);
                ov[p] = ta ? va : vb;
                oi[p] = ta ? ia : ib;
                pa += ta ? 1 : 0;
                pb += ta ? 0 : 1;
            }
#pragma unroll
            for (int p = 0; p < K_TOP; ++p) { mv[a + p] = ov[p]; mi[a + p] = oi[p]; }
        }
        __syncthreads();
    }

    if (tid == 0) {
#pragma unroll
        for (int p = 0; p < K_TOP; ++p) topk[row * K_TOP + p] = mi[p];
    }
}

// ---------------- K4: mutual-NN lists (V) ----------------

__global__ __launch_bounds__(256) void mutual_kernel(
    const int* __restrict__ topk, int* __restrict__ vnbr, int* __restrict__ vcnt)
{
    int i = blockIdx.x * 256 + threadIdx.x;
    if (i >= NN) return;
    int mine[K_TOP];
#pragma unroll
    for (int a = 0; a < K_TOP; ++a) mine[a] = topk[i * K_TOP + a];
    int cnt = 0;
    int out[K_TOP];
#pragma unroll
    for (int a = 0; a < K_TOP; ++a) {
        int j = mine[a];
        bool found = false;
#pragma unroll
        for (int b = 0; b < K_TOP; ++b) found |= (topk[j * K_TOP + b] == i);
        if (found) out[cnt++] = j;
    }
    vcnt[i] = cnt;
    for (int a = 0; a < cnt; ++a) vnbr[i * K_TOP + a] = out[a];
    for (int a = cnt; a < K_TOP; ++a) vnbr[i * K_TOP + a] = -1;
}

// ---------------- K5: W_C_tilda values (co/deg) ----------------

__global__ __launch_bounds__(256) void wct_kernel(
    const int* __restrict__ vnbr, const int* __restrict__ vcnt, float* __restrict__ wct)
{
    int i = blockIdx.x * 256 + threadIdx.x;
    if (i >= NN) return;
    int cnt = vcnt[i];
    int mine[K_TOP];
#pragma unroll
    for (int a = 0; a < K_TOP; ++a) mine[a] = vnbr[i * K_TOP + a];
    float invdeg = 1.0f / fmaxf((float)cnt, 1.0f);
    for (int a = 0; a < K_TOP; ++a) {
        if (a < cnt) {
            int j = mine[a];
            int cj = vcnt[j];
            int co = 0;
            for (int b = 0; b < cj; ++b) {
                int v = vnbr[j * K_TOP + b];
#pragma unroll
                for (int c = 0; c < K_TOP; ++c)
                    co += (c < cnt && mine[c] == v) ? 1 : 0;
            }
            wct[i * K_TOP + a] = (float)co * invdeg;
        } else {
            wct[i * K_TOP + a] = 0.0f;
        }
    }
}

// ---------------- K6: sparse W_C correction ----------------

__global__ __launch_bounds__(256) void corr_kernel(
    const int* __restrict__ topk, const int* __restrict__ vnbr, const int* __restrict__ vcnt,
    const float* __restrict__ wct, const float* __restrict__ Sraw,
    const float* __restrict__ invm, double* __restrict__ partial)
{
    int r = blockIdx.x * 256 + threadIdx.x;
    double acc = 0.0;
    if (r < NN) {
        float im_r = invm[r];
        for (int a = 0; a < K_HALF; ++a) {
            int k = topk[r * K_TOP + a];
            int ck = vcnt[k];
            for (int b = 0; b < ck; ++b) {
                int c = vnbr[k * K_TOP + b];
                if (c == r) continue;
                float w = wct[k * K_TOP + b];
                float sr = Sraw[(size_t)r * NN + c];
                float s1 = sr * im_r;
                float r1 = fmaxf(1.0f - s1, 0.0f);
                float g1 = s1 * s1 - r1 * r1;
                float s2 = sr * invm[c];
                float r2 = fmaxf(1.0f - s2, 0.0f);
                float g2 = s2 * s2 - r2 * r2;
                acc += (double)(w * (g1 + g2)) * (1.0 / 20.0);
            }
        }
    }
    __shared__ double red[256];
    double total = block_reduce_sum_d(acc, red);
    if (threadIdx.x == 0) partial[blockIdx.x] = total;
}

// ---------------- K7: dense loss part ----------------

__global__ __launch_bounds__(256) void dense_kernel(
    const float* __restrict__ Sraw, const float* __restrict__ WP,
    const float* __restrict__ invm, double* __restrict__ partial)
{
    int row = blockIdx.x, tid = threadIdx.x;
    const float4* S4 = (const float4*)(Sraw + (size_t)row * NN);
    const float4* W4 = (const float4*)(WP + (size_t)row * NN);
    float im = invm[row];
    double acc = 0.0;
    for (int j4 = tid; j4 < NN / 4; j4 += 256) {
        float4 sv = S4[j4];
        float4 wv = W4[j4];
        float ss[4] = {sv.x, sv.y, sv.z, sv.w};
        float ww[4] = {wv.x, wv.y, wv.z, wv.w};
#pragma unroll
        for (int c = 0; c < 4; ++c) {
            int j = j4 * 4 + c;
            if (j == row) continue;
            float sc = ss[c] * im;
            float rr = fmaxf(1.0f - sc, 0.0f);
            float term = rr * rr + 0.5f * ww[c] * (sc * sc - rr * rr);
            acc += (double)term;
        }
    }
    __shared__ double red[256];
    double total = block_reduce_sum_d(acc, red);
    if (tid == 0) partial[row] = total;
}

// ---------------- K8: final reduce ----------------

__global__ __launch_bounds__(256) void final_kernel(
    const double* __restrict__ pDense, const double* __restrict__ pCorr, float* __restrict__ out)
{
    int tid = threadIdx.x;
    double a = 0.0;
    for (int j = tid; j < NN; j += 256) a += pDense[j];
    if (tid < 16) a += pCorr[tid];
    __shared__ double red[256];
    double total = block_reduce_sum_d(a, red);
    if (tid == 0) out[0] = (float)(total / ((double)NN * (double)(NN - 1)));
}

// ---------------- launcher ----------------

extern "C" void kernel_launch(void* const* d_in, const int* in_sizes, int n_in,
                              void* d_out, int out_size, void* d_ws, size_t ws_size,
                              hipStream_t stream)
{
    const float* s = (const float*)d_in[0];
    const float* t = (const float*)d_in[1];
    const int* idx = (const int*)d_in[2];
    float* out = (float*)d_out;

    char* base = (char*)d_ws;
    size_t off = 0;
    auto alloc = [&](size_t bytes) -> void* {
        void* p = base + off;
        off = (off + bytes + 511) & ~(size_t)511;
        return p;
    };

    float* Sraw = (float*)alloc((size_t)NN * NN * 4);
    float* WP   = (float*)alloc((size_t)NN * NN * 4);
    unsigned short* hi = (unsigned short*)alloc((size_t)NN * DD * 2);
    unsigned short* lo = (unsigned short*)alloc((size_t)NN * DD * 2);
    float* sn2  = (float*)alloc(NN * 4);
    float* tn2  = (float*)alloc(NN * 4);
    float* invm = (float*)alloc(NN * 4);
    int* topk   = (int*)alloc(NN * K_TOP * 4);
    int* vnbr   = (int*)alloc(NN * K_TOP * 4);
    int* vcnt   = (int*)alloc(NN * 4);
    float* wct  = (float*)alloc(NN * K_TOP * 4);
    double* pDense = (double*)alloc(NN * 8);
    double* pCorr  = (double*)alloc(16 * 8);
    (void)ws_size;

    dim3 ggrid(NN / BM, NN / BM);

    prep_kernel<<<NN, 256, 0, stream>>>(s, t, hi, lo, sn2, tn2);
    gram_mfma_kernel<0><<<ggrid, 256, 0, stream>>>(hi, lo, sn2, Sraw);
    prep2_kernel<<<NN, 256, 0, stream>>>(t, hi, lo);
    gram_mfma_kernel<1><<<ggrid, 256, 0, stream>>>(hi, lo, tn2, WP);

    rowmean_kernel<<<NN, 256, 0, stream>>>(Sraw, invm);
    topk_kernel<<<NN, 256, 0, stream>>>(WP, idx, topk);
    mutual_kernel<<<NN / 256, 256, 0, stream>>>(topk, vnbr, vcnt);
    wct_kernel<<<NN / 256, 256, 0, stream>>>(vnbr, vcnt, wct);
    corr_kernel<<<NN / 256, 256, 0, stream>>>(topk, vnbr, vcnt, wct, Sraw, invm, pCorr);
    dense_kernel<<<NN, 256, 0, stream>>>(Sraw, WP, invm, pDense);
    final_kernel<<<1, 256, 0, stream>>>(pDense, pCorr, out);
}

// Round 4
// 274.895 us; speedup vs baseline: 2.5454x; 1.0885x over previous
//
#include <hip/hip_runtime.h>
#include <math.h>

#define NN 4096
#define DD 512
#define K_TOP 10
#define K_HALF 5

typedef short bf16x8 __attribute__((ext_vector_type(8)));
typedef float f32x4 __attribute__((ext_vector_type(4)));
typedef unsigned short ushort8v __attribute__((ext_vector_type(8)));

// ---------------- helpers ----------------

__device__ inline float block_reduce_sum_f(float v, float* red) {
    int tid = threadIdx.x;
    red[tid] = v;
    __syncthreads();
    for (int st = 128; st > 0; st >>= 1) {
        if (tid < st) red[tid] += red[tid + st];
        __syncthreads();
    }
    float r = red[0];
    __syncthreads();
    return r;
}

__device__ inline double block_reduce_sum_d(double v, double* red) {
    int tid = threadIdx.x;
    red[tid] = v;
    __syncthreads();
    for (int st = 128; st > 0; st >>= 1) {
        if (tid < st) red[tid] += red[tid + st];
        __syncthreads();
    }
    double r = red[0];
    __syncthreads();
    return r;
}

__device__ inline unsigned short f2bf(float x) {
    unsigned u = __float_as_uint(x);
    unsigned r = (u + 0x7fffu + ((u >> 16) & 1u)) >> 16;
    return (unsigned short)r;
}

__device__ inline float bf2f(unsigned short b) {
    unsigned u = ((unsigned)b) << 16;
    return __uint_as_float(u);
}

__device__ inline void gload_lds16(const void* g, void* l) {
    __builtin_amdgcn_global_load_lds((const __attribute__((address_space(1))) void*)g,
                                     (__attribute__((address_space(3))) void*)l, 16, 0, 0);
}

// ---------------- K0: norms + s hi/lo split ----------------

__global__ __launch_bounds__(256) void prep_kernel(
    const float* __restrict__ s, const float* __restrict__ t,
    unsigned short* __restrict__ hi, unsigned short* __restrict__ lo,
    float* __restrict__ sn2, float* __restrict__ tn2)
{
    int row = blockIdx.x;
    int tid = threadIdx.x;
    const float* srow = s + (size_t)row * DD;
    const float* trow = t + (size_t)row * DD;
    float s0 = srow[tid], s1 = srow[tid + 256];
    float t0 = trow[tid], t1 = trow[tid + 256];
    __shared__ float red[256];
    float ssum = block_reduce_sum_f(s0 * s0 + s1 * s1, red);
    float tsum = block_reduce_sum_f(t0 * t0 + t1 * t1, red);
    float nrm = fmaxf(sqrtf(tsum), 1e-12f);
    float u0 = t0 / nrm, u1 = t1 / nrm;
    float usum = block_reduce_sum_f(u0 * u0 + u1 * u1, red);
    unsigned short h0 = f2bf(s0), h1 = f2bf(s1);
    float l0 = s0 - bf2f(h0), l1 = s1 - bf2f(h1);
    hi[(size_t)row * DD + tid] = h0;
    hi[(size_t)row * DD + tid + 256] = h1;
    lo[(size_t)row * DD + tid] = f2bf(l0);
    lo[(size_t)row * DD + tid + 256] = f2bf(l1);
    if (tid == 0) {
        sn2[row] = ssum;
        tn2[row] = usum;
    }
}

// ---------------- K0b: tn hi/lo split ----------------

__global__ __launch_bounds__(256) void prep2_kernel(
    const float* __restrict__ t,
    unsigned short* __restrict__ hi, unsigned short* __restrict__ lo)
{
    int row = blockIdx.x;
    int tid = threadIdx.x;
    const float* trow = t + (size_t)row * DD;
    float t0 = trow[tid], t1 = trow[tid + 256];
    __shared__ float red[256];
    float tsum = block_reduce_sum_f(t0 * t0 + t1 * t1, red);
    float nrm = fmaxf(sqrtf(tsum), 1e-12f);
    float u0 = t0 / nrm, u1 = t1 / nrm;
    unsigned short h0 = f2bf(u0), h1 = f2bf(u1);
    float l0 = u0 - bf2f(h0), l1 = u1 - bf2f(h1);
    hi[(size_t)row * DD + tid] = h0;
    hi[(size_t)row * DD + tid + 256] = h1;
    lo[(size_t)row * DD + tid] = f2bf(l0);
    lo[(size_t)row * DD + tid + 256] = f2bf(l1);
}

// ---------------- K1: symmetric MFMA Gram, bf16 out, swizzled LDS ----------------
// Upper-triangle tiles only; off-diagonal tiles also write mirrored transpose.
// MODE 0: sqrt(max(d2,0))   MODE 1: exp(-max(d2,0))

#define BM 128
#define BK 32

template <int MODE>
__global__ __launch_bounds__(256) void gram_mfma_kernel(
    const unsigned short* __restrict__ Xhi, const unsigned short* __restrict__ Xlo,
    const float* __restrict__ xsq, unsigned short* __restrict__ out)
{
    __shared__ unsigned short lsAh[BM * BK];
    __shared__ unsigned short lsAl[BM * BK];
    __shared__ unsigned short lsBh[BM * BK];
    __shared__ unsigned short lsBl[BM * BK];

    // triangular decode: block q -> (bi, bj), bi <= bj
    int q = blockIdx.x;
    int bi = 0;
    while (q >= (NN / BM - bi)) { q -= (NN / BM - bi); ++bi; }
    int bj = bi + q;
    int i0 = bi * BM, j0 = bj * BM;

    int t = threadIdx.x;
    int wave = t >> 6, lane = t & 63;
    int wr = wave >> 1, wc = wave & 1;

    f32x4 acc[4][4] = {};

    int srow = t >> 2;                       // 0..63 (row within 64-row half)
    int slot = t & 3;                        // LDS 16B slot within row
    int ksrc = slot ^ ((srow >> 1) & 3);     // pre-swizzled global column chunk
    int scol = ksrc * 8;

    for (int k0 = 0; k0 < DD; k0 += BK) {
#pragma unroll
        for (int p = 0; p < 2; ++p) {
            size_t ga = (size_t)(i0 + p * 64 + srow) * DD + k0 + scol;
            size_t gb = (size_t)(j0 + p * 64 + srow) * DD + k0 + scol;
            int lofs = p * 2048 + t * 8;
            gload_lds16(Xhi + ga, &lsAh[lofs]);
            gload_lds16(Xlo + ga, &lsAl[lofs]);
            gload_lds16(Xhi + gb, &lsBh[lofs]);
            gload_lds16(Xlo + gb, &lsBl[lofs]);
        }
        __syncthreads();

        int fr = lane & 15, kg = lane >> 4;
        bf16x8 ah[4], al[4], bh[4], bl[4];
#pragma unroll
        for (int m = 0; m < 4; ++m) {
            int row = wr * 64 + m * 16 + fr;
            int sofs = row * BK + ((kg ^ ((row >> 1) & 3)) << 3);
            ah[m] = *(const bf16x8*)&lsAh[sofs];
            al[m] = *(const bf16x8*)&lsAl[sofs];
        }
#pragma unroll
        for (int n = 0; n < 4; ++n) {
            int row = wc * 64 + n * 16 + fr;
            int sofs = row * BK + ((kg ^ ((row >> 1) & 3)) << 3);
            bh[n] = *(const bf16x8*)&lsBh[sofs];
            bl[n] = *(const bf16x8*)&lsBl[sofs];
        }
#pragma unroll
        for (int m = 0; m < 4; ++m)
#pragma unroll
            for (int n = 0; n < 4; ++n) {
                acc[m][n] = __builtin_amdgcn_mfma_f32_16x16x32_bf16(ah[m], bh[n], acc[m][n], 0, 0, 0);
                acc[m][n] = __builtin_amdgcn_mfma_f32_16x16x32_bf16(ah[m], bl[n], acc[m][n], 0, 0, 0);
                acc[m][n] = __builtin_amdgcn_mfma_f32_16x16x32_bf16(al[m], bh[n], acc[m][n], 0, 0, 0);
            }
        __syncthreads();
    }

    // epilogue: C/D layout col = lane&15, row = (lane>>4)*4 + reg
    int fr = lane & 15, fq = lane >> 4;
    float xj[4];
#pragma unroll
    for (int n = 0; n < 4; ++n) xj[n] = xsq[j0 + wc * 64 + n * 16 + fr];
    bool mirror = (bi != bj);
#pragma unroll
    for (int m = 0; m < 4; ++m) {
        int ibase = i0 + wr * 64 + m * 16 + fq * 4;
        float xi[4];
#pragma unroll
        for (int r = 0; r < 4; ++r) xi[r] = xsq[ibase + r];
#pragma unroll
        for (int n = 0; n < 4; ++n) {
            int j = j0 + wc * 64 + n * 16 + fr;
            unsigned short pk[4];
#pragma unroll
            for (int r = 0; r < 4; ++r) {
                float d2 = xi[r] + xj[n] - 2.0f * acc[m][n][r];
                d2 = fmaxf(d2, 0.0f);
                float v = (MODE == 0) ? sqrtf(d2) : expf(-d2);
                pk[r] = f2bf(v);
                out[(size_t)(ibase + r) * NN + j] = pk[r];
            }
            if (mirror) {
                ushort4 u4;
                u4.x = pk[0]; u4.y = pk[1]; u4.z = pk[2]; u4.w = pk[3];
                *(ushort4*)&out[(size_t)j * NN + ibase] = u4;
            }
        }
    }
}

// ---------------- K2: row mean (bf16 input) -> inverse mean ----------------

__global__ __launch_bounds__(256) void rowmean_kernel(
    const unsigned short* __restrict__ Sb, float* __restrict__ invm)
{
    int row = blockIdx.x, tid = threadIdx.x;
    const ushort8v* p = (const ushort8v*)(Sb + (size_t)row * NN);
    float acc = 0.f;
#pragma unroll
    for (int q = 0; q < 2; ++q) {
        ushort8v v = p[tid + 256 * q];
        float a = 0.f;
#pragma unroll
        for (int c = 0; c < 8; ++c) a += bf2f(v[c]);
        acc += a;
    }
    __shared__ float red[256];
    float total = block_reduce_sum_f(acc, red);
    if (tid == 0) {
        float mean = total / (float)NN;
        invm[row] = 1.0f / mean;
    }
}

// ---------------- K3: per-row stable top-10 (bf16 input) ----------------

__global__ __launch_bounds__(256) void topk_kernel(
    const unsigned short* __restrict__ Wb, const int* __restrict__ idx, int* __restrict__ topk)
{
    __shared__ float mv[256 * K_TOP];
    __shared__ int   mi[256 * K_TOP];
    int row = blockIdx.x, tid = threadIdx.x;
    int myidx = idx[row];
    const ushort8v* w8 = (const ushort8v*)(Wb + (size_t)row * NN);
    const int4* i4 = (const int4*)idx;

    float v[K_TOP];
    int id[K_TOP];
#pragma unroll
    for (int p = 0; p < K_TOP; ++p) { v[p] = -2.0f; id[p] = 0x7fffffff; }

#pragma unroll
    for (int q = 0; q < 2; ++q) {
        int j8 = tid + 256 * q;
        ushort8v wv = w8[j8];
        int4 ia = i4[j8 * 2];
        int4 ib = i4[j8 * 2 + 1];
        int ii[8] = {ia.x, ia.y, ia.z, ia.w, ib.x, ib.y, ib.z, ib.w};
#pragma unroll
        for (int c = 0; c < 8; ++c) {
            int j = j8 * 8 + c;
            float nv = (ii[c] == myidx) ? 1.0f : bf2f(wv[c]);
#pragma unroll
            for (int p = K_TOP - 1; p >= 1; --p) {
                if (nv > v[p - 1]) { v[p] = v[p - 1]; id[p] = id[p - 1]; }
                else if (nv > v[p]) { v[p] = nv; id[p] = j; }
            }
            if (nv > v[0]) { v[0] = nv; id[0] = j; }
        }
    }

#pragma unroll
    for (int p = 0; p < K_TOP; ++p) { mv[tid * K_TOP + p] = v[p]; mi[tid * K_TOP + p] = id[p]; }
    __syncthreads();

    for (int stride = 128; stride >= 1; stride >>= 1) {
        if (tid < stride) {
            int a = tid * K_TOP, b = (tid + stride) * K_TOP;
            float ov[K_TOP];
            int oi[K_TOP];
            int pa = 0, pb = 0;
#pragma unroll
            for (int p = 0; p < K_TOP; ++p) {
                float va = mv[a + pa], vb = mv[b + pb];
                int ia = mi[a + pa], ib = mi[b + pb];
                bool ta = (va > vb) || (va == vb && ia < ib);
                ov[p] = ta ? va : vb;
                oi[p] = ta ? ia : ib;
                pa += ta ? 1 : 0;
                pb += ta ? 0 : 1;
            }
#pragma unroll
            for (int p = 0; p < K_TOP; ++p) { mv[a + p] = ov[p]; mi[a + p] = oi[p]; }
        }
        __syncthreads();
    }

    if (tid == 0) {
#pragma unroll
        for (int p = 0; p < K_TOP; ++p) topk[row * K_TOP + p] = mi[p];
    }
}

// ---------------- K4: mutual-NN lists (V) ----------------

__global__ __launch_bounds__(256) void mutual_kernel(
    const int* __restrict__ topk, int* __restrict__ vnbr, int* __restrict__ vcnt)
{
    int i = blockIdx.x * 256 + threadIdx.x;
    if (i >= NN) return;
    int mine[K_TOP];
#pragma unroll
    for (int a = 0; a < K_TOP; ++a) mine[a] = topk[i * K_TOP + a];
    int cnt = 0;
    int out[K_TOP];
#pragma unroll
    for (int a = 0; a < K_TOP; ++a) {
        int j = mine[a];
        bool found = false;
#pragma unroll
        for (int b = 0; b < K_TOP; ++b) found |= (topk[j * K_TOP + b] == i);
        if (found) out[cnt++] = j;
    }
    vcnt[i] = cnt;
    for (int a = 0; a < cnt; ++a) vnbr[i * K_TOP + a] = out[a];
    for (int a = cnt; a < K_TOP; ++a) vnbr[i * K_TOP + a] = -1;
}

// ---------------- K5: W_C_tilda values (co/deg) ----------------

__global__ __launch_bounds__(256) void wct_kernel(
    const int* __restrict__ vnbr, const int* __restrict__ vcnt, float* __restrict__ wct)
{
    int i = blockIdx.x * 256 + threadIdx.x;
    if (i >= NN) return;
    int cnt = vcnt[i];
    int mine[K_TOP];
#pragma unroll
    for (int a = 0; a < K_TOP; ++a) mine[a] = vnbr[i * K_TOP + a];
    float invdeg = 1.0f / fmaxf((float)cnt, 1.0f);
    for (int a = 0; a < K_TOP; ++a) {
        if (a < cnt) {
            int j = mine[a];
            int cj = vcnt[j];
            int co = 0;
            for (int b = 0; b < cj; ++b) {
                int v = vnbr[j * K_TOP + b];
#pragma unroll
                for (int c = 0; c < K_TOP; ++c)
                    co += (c < cnt && mine[c] == v) ? 1 : 0;
            }
            wct[i * K_TOP + a] = (float)co * invdeg;
        } else {
            wct[i * K_TOP + a] = 0.0f;
        }
    }
}

// ---------------- K6: sparse W_C correction ----------------

__global__ __launch_bounds__(256) void corr_kernel(
    const int* __restrict__ topk, const int* __restrict__ vnbr, const int* __restrict__ vcnt,
    const float* __restrict__ wct, const unsigned short* __restrict__ Sb,
    const float* __restrict__ invm, double* __restrict__ partial)
{
    int r = blockIdx.x * 256 + threadIdx.x;
    double acc = 0.0;
    if (r < NN) {
        float im_r = invm[r];
        for (int a = 0; a < K_HALF; ++a) {
            int k = topk[r * K_TOP + a];
            int ck = vcnt[k];
            for (int b = 0; b < ck; ++b) {
                int c = vnbr[k * K_TOP + b];
                if (c == r) continue;
                float w = wct[k * K_TOP + b];
                float sr = bf2f(Sb[(size_t)r * NN + c]);
                float s1 = sr * im_r;
                float r1 = fmaxf(1.0f - s1, 0.0f);
                float g1 = s1 * s1 - r1 * r1;
                float s2 = sr * invm[c];
                float r2 = fmaxf(1.0f - s2, 0.0f);
                float g2 = s2 * s2 - r2 * r2;
                acc += (double)(w * (g1 + g2)) * (1.0 / 20.0);
            }
        }
    }
    __shared__ double red[256];
    double total = block_reduce_sum_d(acc, red);
    if (threadIdx.x == 0) partial[blockIdx.x] = total;
}

// ---------------- K7: dense loss part (bf16 inputs) ----------------

__global__ __launch_bounds__(256) void dense_kernel(
    const unsigned short* __restrict__ Sb, const unsigned short* __restrict__ Wb,
    const float* __restrict__ invm, double* __restrict__ partial)
{
    int row = blockIdx.x, tid = threadIdx.x;
    const ushort8v* S8 = (const ushort8v*)(Sb + (size_t)row * NN);
    const ushort8v* W8 = (const ushort8v*)(Wb + (size_t)row * NN);
    float im = invm[row];
    double acc = 0.0;
#pragma unroll
    for (int q = 0; q < 2; ++q) {
        int j8 = tid + 256 * q;
        ushort8v sv = S8[j8];
        ushort8v wv = W8[j8];
        float part = 0.f;
        bool hasdiag = (j8 * 8 <= row) && (row < j8 * 8 + 8);
#pragma unroll
        for (int c = 0; c < 8; ++c) {
            float sc = bf2f(sv[c]) * im;
            float rr = fmaxf(1.0f - sc, 0.0f);
            float term = rr * rr + 0.5f * bf2f(wv[c]) * (sc * sc - rr * rr);
            part += term;
        }
        if (hasdiag) {
            int c = row - j8 * 8;
            float sc = bf2f(sv[c]) * im;
            float rr = fmaxf(1.0f - sc, 0.0f);
            part -= rr * rr + 0.5f * bf2f(wv[c]) * (sc * sc - rr * rr);
        }
        acc += (double)part;
    }
    __shared__ double red[256];
    double total = block_reduce_sum_d(acc, red);
    if (tid == 0) partial[row] = total;
}

// ---------------- K8: final reduce ----------------

__global__ __launch_bounds__(256) void final_kernel(
    const double* __restrict__ pDense, const double* __restrict__ pCorr, float* __restrict__ out)
{
    int tid = threadIdx.x;
    double a = 0.0;
    for (int j = tid; j < NN; j += 256) a += pDense[j];
    if (tid < 16) a += pCorr[tid];
    __shared__ double red[256];
    double total = block_reduce_sum_d(a, red);
    if (tid == 0) out[0] = (float)(total / ((double)NN * (double)(NN - 1)));
}

// ---------------- launcher ----------------

extern "C" void kernel_launch(void* const* d_in, const int* in_sizes, int n_in,
                              void* d_out, int out_size, void* d_ws, size_t ws_size,
                              hipStream_t stream)
{
    const float* s = (const float*)d_in[0];
    const float* t = (const float*)d_in[1];
    const int* idx = (const int*)d_in[2];
    float* out = (float*)d_out;

    char* base = (char*)d_ws;
    size_t off = 0;
    auto alloc = [&](size_t bytes) -> void* {
        void* p = base + off;
        off = (off + bytes + 511) & ~(size_t)511;
        return p;
    };

    unsigned short* Sb = (unsigned short*)alloc((size_t)NN * NN * 2);
    unsigned short* Wb = (unsigned short*)alloc((size_t)NN * NN * 2);
    unsigned short* hi = (unsigned short*)alloc((size_t)NN * DD * 2);
    unsigned short* lo = (unsigned short*)alloc((size_t)NN * DD * 2);
    float* sn2  = (float*)alloc(NN * 4);
    float* tn2  = (float*)alloc(NN * 4);
    float* invm = (float*)alloc(NN * 4);
    int* topk   = (int*)alloc(NN * K_TOP * 4);
    int* vnbr   = (int*)alloc(NN * K_TOP * 4);
    int* vcnt   = (int*)alloc(NN * 4);
    float* wct  = (float*)alloc(NN * K_TOP * 4);
    double* pDense = (double*)alloc(NN * 8);
    double* pCorr  = (double*)alloc(16 * 8);
    (void)ws_size;

    int ntile = NN / BM;
    int ntri = ntile * (ntile + 1) / 2;

    prep_kernel<<<NN, 256, 0, stream>>>(s, t, hi, lo, sn2, tn2);
    gram_mfma_kernel<0><<<ntri, 256, 0, stream>>>(hi, lo, sn2, Sb);
    prep2_kernel<<<NN, 256, 0, stream>>>(t, hi, lo);
    gram_mfma_kernel<1><<<ntri, 256, 0, stream>>>(hi, lo, tn2, Wb);

    rowmean_kernel<<<NN, 256, 0, stream>>>(Sb, invm);
    topk_kernel<<<NN, 256, 0, stream>>>(Wb, idx, topk);
    mutual_kernel<<<NN / 256, 256, 0, stream>>>(topk, vnbr, vcnt);
    wct_kernel<<<NN / 256, 256, 0, stream>>>(vnbr, vcnt, wct);
    corr_kernel<<<NN / 256, 256, 0, stream>>>(topk, vnbr, vcnt, wct, Sb, invm, pCorr);
    dense_kernel<<<NN, 256, 0, stream>>>(Sb, Wb, invm, pDense);
    final_kernel<<<1, 256, 0, stream>>>(pDense, pCorr, out);
}

// Round 5
// 248.434 us; speedup vs baseline: 2.8165x; 1.1065x over previous
//
#include <hip/hip_runtime.h>
#include <math.h>

#define NN 4096
#define DD 512
#define K_TOP 10
#define K_HALF 5

typedef short bf16x8 __attribute__((ext_vector_type(8)));
typedef float f32x4 __attribute__((ext_vector_type(4)));
typedef unsigned short ushort8v __attribute__((ext_vector_type(8)));

// ---------------- helpers ----------------

__device__ inline float block_reduce_sum_f(float v, float* red) {
    int tid = threadIdx.x;
    red[tid] = v;
    __syncthreads();
    for (int st = 128; st > 0; st >>= 1) {
        if (tid < st) red[tid] += red[tid + st];
        __syncthreads();
    }
    float r = red[0];
    __syncthreads();
    return r;
}

__device__ inline double block_reduce_sum_d(double v, double* red) {
    int tid = threadIdx.x;
    red[tid] = v;
    __syncthreads();
    for (int st = 128; st > 0; st >>= 1) {
        if (tid < st) red[tid] += red[tid + st];
        __syncthreads();
    }
    double r = red[0];
    __syncthreads();
    return r;
}

__device__ inline unsigned short f2bf(float x) {
    unsigned u = __float_as_uint(x);
    unsigned r = (u + 0x7fffu + ((u >> 16) & 1u)) >> 16;
    return (unsigned short)r;
}

__device__ inline float bf2f(unsigned short b) {
    unsigned u = ((unsigned)b) << 16;
    return __uint_as_float(u);
}

__device__ inline void gload_lds16(const void* g, void* l) {
    __builtin_amdgcn_global_load_lds((const __attribute__((address_space(1))) void*)g,
                                     (__attribute__((address_space(3))) void*)l, 16, 0, 0);
}

// ---------------- K0: norms + all four hi/lo splits ----------------

__global__ __launch_bounds__(256) void prep_kernel(
    const float* __restrict__ s, const float* __restrict__ t,
    unsigned short* __restrict__ shi, unsigned short* __restrict__ slo,
    unsigned short* __restrict__ thi, unsigned short* __restrict__ tlo,
    float* __restrict__ sn2, float* __restrict__ tn2)
{
    int row = blockIdx.x;
    int tid = threadIdx.x;
    const float* srow = s + (size_t)row * DD;
    const float* trow = t + (size_t)row * DD;
    float s0 = srow[tid], s1 = srow[tid + 256];
    float t0 = trow[tid], t1 = trow[tid + 256];
    __shared__ float red[256];
    float ssum = block_reduce_sum_f(s0 * s0 + s1 * s1, red);
    float tsum = block_reduce_sum_f(t0 * t0 + t1 * t1, red);
    float nrm = fmaxf(sqrtf(tsum), 1e-12f);
    float u0 = t0 / nrm, u1 = t1 / nrm;
    float usum = block_reduce_sum_f(u0 * u0 + u1 * u1, red);
    // s splits
    unsigned short h0 = f2bf(s0), h1 = f2bf(s1);
    float l0 = s0 - bf2f(h0), l1 = s1 - bf2f(h1);
    shi[(size_t)row * DD + tid] = h0;
    shi[(size_t)row * DD + tid + 256] = h1;
    slo[(size_t)row * DD + tid] = f2bf(l0);
    slo[(size_t)row * DD + tid + 256] = f2bf(l1);
    // tn splits
    unsigned short g0 = f2bf(u0), g1 = f2bf(u1);
    float m0 = u0 - bf2f(g0), m1 = u1 - bf2f(g1);
    thi[(size_t)row * DD + tid] = g0;
    thi[(size_t)row * DD + tid + 256] = g1;
    tlo[(size_t)row * DD + tid] = f2bf(m0);
    tlo[(size_t)row * DD + tid + 256] = f2bf(m1);
    if (tid == 0) {
        sn2[row] = ssum;
        tn2[row] = usum;
    }
}

// ---------------- K1: fused symmetric MFMA Gram (both matrices, one dispatch) ----------------
// blocks [0, ntri)        : S gram  -> Sb = sqrt(max(d2,0))
// blocks [ntri, 2*ntri)   : T gram  -> Wb = exp(-max(d2,0))

#define BM 128
#define BK 32

__global__ __launch_bounds__(256) void gram_fused_kernel(
    const unsigned short* __restrict__ shi, const unsigned short* __restrict__ slo,
    const unsigned short* __restrict__ thi, const unsigned short* __restrict__ tlo,
    const float* __restrict__ sn2, const float* __restrict__ tn2,
    unsigned short* __restrict__ Sb, unsigned short* __restrict__ Wb, int ntri)
{
    __shared__ unsigned short lsAh[BM * BK];
    __shared__ unsigned short lsAl[BM * BK];
    __shared__ unsigned short lsBh[BM * BK];
    __shared__ unsigned short lsBl[BM * BK];

    int bid = blockIdx.x;
    bool isS = (bid < ntri);
    int q = isS ? bid : bid - ntri;
    const unsigned short* Xhi = isS ? shi : thi;
    const unsigned short* Xlo = isS ? slo : tlo;
    const float* xsq = isS ? sn2 : tn2;
    unsigned short* out = isS ? Sb : Wb;

    // triangular decode: q -> (bi, bj), bi <= bj
    int bi = 0;
    while (q >= (NN / BM - bi)) { q -= (NN / BM - bi); ++bi; }
    int bj = bi + q;
    int i0 = bi * BM, j0 = bj * BM;

    int t = threadIdx.x;
    int wave = t >> 6, lane = t & 63;
    int wr = wave >> 1, wc = wave & 1;

    f32x4 acc[4][4] = {};

    int srow = t >> 2;                       // 0..63 (row within 64-row half)
    int slot = t & 3;                        // LDS 16B slot within row
    int ksrc = slot ^ ((srow >> 1) & 3);     // pre-swizzled global column chunk
    int scol = ksrc * 8;

    for (int k0 = 0; k0 < DD; k0 += BK) {
#pragma unroll
        for (int p = 0; p < 2; ++p) {
            size_t ga = (size_t)(i0 + p * 64 + srow) * DD + k0 + scol;
            size_t gb = (size_t)(j0 + p * 64 + srow) * DD + k0 + scol;
            int lofs = p * 2048 + t * 8;
            gload_lds16(Xhi + ga, &lsAh[lofs]);
            gload_lds16(Xlo + ga, &lsAl[lofs]);
            gload_lds16(Xhi + gb, &lsBh[lofs]);
            gload_lds16(Xlo + gb, &lsBl[lofs]);
        }
        __syncthreads();

        int fr = lane & 15, kg = lane >> 4;
        bf16x8 ah[4], al[4], bh[4], bl[4];
#pragma unroll
        for (int m = 0; m < 4; ++m) {
            int row = wr * 64 + m * 16 + fr;
            int sofs = row * BK + ((kg ^ ((row >> 1) & 3)) << 3);
            ah[m] = *(const bf16x8*)&lsAh[sofs];
            al[m] = *(const bf16x8*)&lsAl[sofs];
        }
#pragma unroll
        for (int n = 0; n < 4; ++n) {
            int row = wc * 64 + n * 16 + fr;
            int sofs = row * BK + ((kg ^ ((row >> 1) & 3)) << 3);
            bh[n] = *(const bf16x8*)&lsBh[sofs];
            bl[n] = *(const bf16x8*)&lsBl[sofs];
        }
#pragma unroll
        for (int m = 0; m < 4; ++m)
#pragma unroll
            for (int n = 0; n < 4; ++n) {
                acc[m][n] = __builtin_amdgcn_mfma_f32_16x16x32_bf16(ah[m], bh[n], acc[m][n], 0, 0, 0);
                acc[m][n] = __builtin_amdgcn_mfma_f32_16x16x32_bf16(ah[m], bl[n], acc[m][n], 0, 0, 0);
                acc[m][n] = __builtin_amdgcn_mfma_f32_16x16x32_bf16(al[m], bh[n], acc[m][n], 0, 0, 0);
            }
        __syncthreads();
    }

    // epilogue: C/D layout col = lane&15, row = (lane>>4)*4 + reg
    int fr = lane & 15, fq = lane >> 4;
    float xj[4];
#pragma unroll
    for (int n = 0; n < 4; ++n) xj[n] = xsq[j0 + wc * 64 + n * 16 + fr];
    bool mirror = (bi != bj);
#pragma unroll
    for (int m = 0; m < 4; ++m) {
        int ibase = i0 + wr * 64 + m * 16 + fq * 4;
        float xi[4];
#pragma unroll
        for (int r = 0; r < 4; ++r) xi[r] = xsq[ibase + r];
#pragma unroll
        for (int n = 0; n < 4; ++n) {
            int j = j0 + wc * 64 + n * 16 + fr;
            unsigned short pk[4];
#pragma unroll
            for (int r = 0; r < 4; ++r) {
                float d2 = xi[r] + xj[n] - 2.0f * acc[m][n][r];
                d2 = fmaxf(d2, 0.0f);
                float v = isS ? sqrtf(d2) : expf(-d2);
                pk[r] = f2bf(v);
                out[(size_t)(ibase + r) * NN + j] = pk[r];
            }
            if (mirror) {
                ushort4 u4;
                u4.x = pk[0]; u4.y = pk[1]; u4.z = pk[2]; u4.w = pk[3];
                *(ushort4*)&out[(size_t)j * NN + ibase] = u4;
            }
        }
    }
}

// ---------------- K2: row mean (bf16 input) -> inverse mean ----------------

__global__ __launch_bounds__(256) void rowmean_kernel(
    const unsigned short* __restrict__ Sb, float* __restrict__ invm)
{
    int row = blockIdx.x, tid = threadIdx.x;
    const ushort8v* p = (const ushort8v*)(Sb + (size_t)row * NN);
    float acc = 0.f;
#pragma unroll
    for (int q = 0; q < 2; ++q) {
        ushort8v v = p[tid + 256 * q];
        float a = 0.f;
#pragma unroll
        for (int c = 0; c < 8; ++c) a += bf2f(v[c]);
        acc += a;
    }
    __shared__ float red[256];
    float total = block_reduce_sum_f(acc, red);
    if (tid == 0) {
        float mean = total / (float)NN;
        invm[row] = 1.0f / mean;
    }
}

// ---------------- K3: per-row stable top-10 (bf16 input) ----------------

__global__ __launch_bounds__(256) void topk_kernel(
    const unsigned short* __restrict__ Wb, const int* __restrict__ idx, int* __restrict__ topk)
{
    __shared__ float mv[256 * K_TOP];
    __shared__ int   mi[256 * K_TOP];
    int row = blockIdx.x, tid = threadIdx.x;
    int myidx = idx[row];
    const ushort8v* w8 = (const ushort8v*)(Wb + (size_t)row * NN);
    const int4* i4 = (const int4*)idx;

    float v[K_TOP];
    int id[K_TOP];
#pragma unroll
    for (int p = 0; p < K_TOP; ++p) { v[p] = -2.0f; id[p] = 0x7fffffff; }

#pragma unroll
    for (int q = 0; q < 2; ++q) {
        int j8 = tid + 256 * q;
        ushort8v wv = w8[j8];
        int4 ia = i4[j8 * 2];
        int4 ib = i4[j8 * 2 + 1];
        int ii[8] = {ia.x, ia.y, ia.z, ia.w, ib.x, ib.y, ib.z, ib.w};
#pragma unroll
        for (int c = 0; c < 8; ++c) {
            int j = j8 * 8 + c;
            float nv = (ii[c] == myidx) ? 1.0f : bf2f(wv[c]);
#pragma unroll
            for (int p = K_TOP - 1; p >= 1; --p) {
                if (nv > v[p - 1]) { v[p] = v[p - 1]; id[p] = id[p - 1]; }
                else if (nv > v[p]) { v[p] = nv; id[p] = j; }
            }
            if (nv > v[0]) { v[0] = nv; id[0] = j; }
        }
    }

#pragma unroll
    for (int p = 0; p < K_TOP; ++p) { mv[tid * K_TOP + p] = v[p]; mi[tid * K_TOP + p] = id[p]; }
    __syncthreads();

    for (int stride = 128; stride >= 1; stride >>= 1) {
        if (tid < stride) {
            int a = tid * K_TOP, b = (tid + stride) * K_TOP;
            float ov[K_TOP];
            int oi[K_TOP];
            int pa = 0, pb = 0;
#pragma unroll
            for (int p = 0; p < K_TOP; ++p) {
                float va = mv[a + pa], vb = mv[b + pb];
                int ia = mi[a + pa], ib = mi[b + pb];
                bool ta = (va > vb) || (va == vb && ia < ib);
                ov[p] = ta ? va : vb;
                oi[p] = ta ? ia : ib;
                pa += ta ? 1 : 0;
                pb += ta ? 0 : 1;
            }
#pragma unroll
            for (int p = 0; p < K_TOP; ++p) { mv[a + p] = ov[p]; mi[a + p] = oi[p]; }
        }
        __syncthreads();
    }

    if (tid == 0) {
#pragma unroll
        for (int p = 0; p < K_TOP; ++p) topk[row * K_TOP + p] = mi[p];
    }
}

// ---------------- K4: mutual-NN lists (V) ----------------

__global__ __launch_bounds__(256) void mutual_kernel(
    const int* __restrict__ topk, int* __restrict__ vnbr, int* __restrict__ vcnt)
{
    int i = blockIdx.x * 256 + threadIdx.x;
    if (i >= NN) return;
    int mine[K_TOP];
#pragma unroll
    for (int a = 0; a < K_TOP; ++a) mine[a] = topk[i * K_TOP + a];
    int cnt = 0;
    int out[K_TOP];
#pragma unroll
    for (int a = 0; a < K_TOP; ++a) {
        int j = mine[a];
        bool found = false;
#pragma unroll
        for (int b = 0; b < K_TOP; ++b) found |= (topk[j * K_TOP + b] == i);
        if (found) out[cnt++] = j;
    }
    vcnt[i] = cnt;
    for (int a = 0; a < cnt; ++a) vnbr[i * K_TOP + a] = out[a];
    for (int a = cnt; a < K_TOP; ++a) vnbr[i * K_TOP + a] = -1;
}

// ---------------- K5: W_C_tilda values (co/deg) ----------------

__global__ __launch_bounds__(256) void wct_kernel(
    const int* __restrict__ vnbr, const int* __restrict__ vcnt, float* __restrict__ wct)
{
    int i = blockIdx.x * 256 + threadIdx.x;
    if (i >= NN) return;
    int cnt = vcnt[i];
    int mine[K_TOP];
#pragma unroll
    for (int a = 0; a < K_TOP; ++a) mine[a] = vnbr[i * K_TOP + a];
    float invdeg = 1.0f / fmaxf((float)cnt, 1.0f);
    for (int a = 0; a < K_TOP; ++a) {
        if (a < cnt) {
            int j = mine[a];
            int cj = vcnt[j];
            int co = 0;
            for (int b = 0; b < cj; ++b) {
                int v = vnbr[j * K_TOP + b];
#pragma unroll
                for (int c = 0; c < K_TOP; ++c)
                    co += (c < cnt && mine[c] == v) ? 1 : 0;
            }
            wct[i * K_TOP + a] = (float)co * invdeg;
        } else {
            wct[i * K_TOP + a] = 0.0f;
        }
    }
}

// ---------------- K6: sparse W_C correction ----------------

__global__ __launch_bounds__(256) void corr_kernel(
    const int* __restrict__ topk, const int* __restrict__ vnbr, const int* __restrict__ vcnt,
    const float* __restrict__ wct, const unsigned short* __restrict__ Sb,
    const float* __restrict__ invm, double* __restrict__ partial)
{
    int r = blockIdx.x * 256 + threadIdx.x;
    double acc = 0.0;
    if (r < NN) {
        float im_r = invm[r];
        for (int a = 0; a < K_HALF; ++a) {
            int k = topk[r * K_TOP + a];
            int ck = vcnt[k];
            for (int b = 0; b < ck; ++b) {
                int c = vnbr[k * K_TOP + b];
                if (c == r) continue;
                float w = wct[k * K_TOP + b];
                float sr = bf2f(Sb[(size_t)r * NN + c]);
                float s1 = sr * im_r;
                float r1 = fmaxf(1.0f - s1, 0.0f);
                float g1 = s1 * s1 - r1 * r1;
                float s2 = sr * invm[c];
                float r2 = fmaxf(1.0f - s2, 0.0f);
                float g2 = s2 * s2 - r2 * r2;
                acc += (double)(w * (g1 + g2)) * (1.0 / 20.0);
            }
        }
    }
    __shared__ double red[256];
    double total = block_reduce_sum_d(acc, red);
    if (threadIdx.x == 0) partial[blockIdx.x] = total;
}

// ---------------- K7: dense loss part (bf16 inputs) ----------------

__global__ __launch_bounds__(256) void dense_kernel(
    const unsigned short* __restrict__ Sb, const unsigned short* __restrict__ Wb,
    const float* __restrict__ invm, double* __restrict__ partial)
{
    int row = blockIdx.x, tid = threadIdx.x;
    const ushort8v* S8 = (const ushort8v*)(Sb + (size_t)row * NN);
    const ushort8v* W8 = (const ushort8v*)(Wb + (size_t)row * NN);
    float im = invm[row];
    double acc = 0.0;
#pragma unroll
    for (int q = 0; q < 2; ++q) {
        int j8 = tid + 256 * q;
        ushort8v sv = S8[j8];
        ushort8v wv = W8[j8];
        float part = 0.f;
        bool hasdiag = (j8 * 8 <= row) && (row < j8 * 8 + 8);
#pragma unroll
        for (int c = 0; c < 8; ++c) {
            float sc = bf2f(sv[c]) * im;
            float rr = fmaxf(1.0f - sc, 0.0f);
            float term = rr * rr + 0.5f * bf2f(wv[c]) * (sc * sc - rr * rr);
            part += term;
        }
        if (hasdiag) {
            int c = row - j8 * 8;
            float sc = bf2f(sv[c]) * im;
            float rr = fmaxf(1.0f - sc, 0.0f);
            part -= rr * rr + 0.5f * bf2f(wv[c]) * (sc * sc - rr * rr);
        }
        acc += (double)part;
    }
    __shared__ double red[256];
    double total = block_reduce_sum_d(acc, red);
    if (tid == 0) partial[row] = total;
}

// ---------------- K8: final reduce ----------------

__global__ __launch_bounds__(256) void final_kernel(
    const double* __restrict__ pDense, const double* __restrict__ pCorr, float* __restrict__ out)
{
    int tid = threadIdx.x;
    double a = 0.0;
    for (int j = tid; j < NN; j += 256) a += pDense[j];
    if (tid < 16) a += pCorr[tid];
    __shared__ double red[256];
    double total = block_reduce_sum_d(a, red);
    if (tid == 0) out[0] = (float)(total / ((double)NN * (double)(NN - 1)));
}

// ---------------- launcher ----------------

extern "C" void kernel_launch(void* const* d_in, const int* in_sizes, int n_in,
                              void* d_out, int out_size, void* d_ws, size_t ws_size,
                              hipStream_t stream)
{
    const float* s = (const float*)d_in[0];
    const float* t = (const float*)d_in[1];
    const int* idx = (const int*)d_in[2];
    float* out = (float*)d_out;

    char* base = (char*)d_ws;
    size_t off = 0;
    auto alloc = [&](size_t bytes) -> void* {
        void* p = base + off;
        off = (off + bytes + 511) & ~(size_t)511;
        return p;
    };

    unsigned short* Sb = (unsigned short*)alloc((size_t)NN * NN * 2);
    unsigned short* Wb = (unsigned short*)alloc((size_t)NN * NN * 2);
    unsigned short* shi = (unsigned short*)alloc((size_t)NN * DD * 2);
    unsigned short* slo = (unsigned short*)alloc((size_t)NN * DD * 2);
    unsigned short* thi = (unsigned short*)alloc((size_t)NN * DD * 2);
    unsigned short* tlo = (unsigned short*)alloc((size_t)NN * DD * 2);
    float* sn2  = (float*)alloc(NN * 4);
    float* tn2  = (float*)alloc(NN * 4);
    float* invm = (float*)alloc(NN * 4);
    int* topk   = (int*)alloc(NN * K_TOP * 4);
    int* vnbr   = (int*)alloc(NN * K_TOP * 4);
    int* vcnt   = (int*)alloc(NN * 4);
    float* wct  = (float*)alloc(NN * K_TOP * 4);
    double* pDense = (double*)alloc(NN * 8);
    double* pCorr  = (double*)alloc(16 * 8);
    (void)ws_size;

    int ntile = NN / BM;
    int ntri = ntile * (ntile + 1) / 2;

    prep_kernel<<<NN, 256, 0, stream>>>(s, t, shi, slo, thi, tlo, sn2, tn2);
    gram_fused_kernel<<<2 * ntri, 256, 0, stream>>>(shi, slo, thi, tlo, sn2, tn2, Sb, Wb, ntri);

    rowmean_kernel<<<NN, 256, 0, stream>>>(Sb, invm);
    topk_kernel<<<NN, 256, 0, stream>>>(Wb, idx, topk);
    mutual_kernel<<<NN / 256, 256, 0, stream>>>(topk, vnbr, vcnt);
    wct_kernel<<<NN / 256, 256, 0, stream>>>(vnbr, vcnt, wct);
    corr_kernel<<<NN / 256, 256, 0, stream>>>(topk, vnbr, vcnt, wct, Sb, invm, pCorr);
    dense_kernel<<<NN, 256, 0, stream>>>(Sb, Wb, invm, pDense);
    final_kernel<<<1, 256, 0, stream>>>(pDense, pCorr, out);
}

// Round 6
// 195.511 us; speedup vs baseline: 3.5789x; 1.2707x over previous
//
#include <hip/hip_runtime.h>
#include <math.h>

#define NN 4096
#define DD 512
#define K_TOP 10
#define K_HALF 5

typedef short bf16x8 __attribute__((ext_vector_type(8)));
typedef float f32x4 __attribute__((ext_vector_type(4)));
typedef unsigned short ushort8v __attribute__((ext_vector_type(8)));

// ---------------- helpers ----------------

__device__ inline float block_reduce_sum_f(float v, float* red) {
    int tid = threadIdx.x;
    red[tid] = v;
    __syncthreads();
    for (int st = 128; st > 0; st >>= 1) {
        if (tid < st) red[tid] += red[tid + st];
        __syncthreads();
    }
    float r = red[0];
    __syncthreads();
    return r;
}

__device__ inline double block_reduce_sum_d(double v, double* red) {
    int tid = threadIdx.x;
    red[tid] = v;
    __syncthreads();
    for (int st = 128; st > 0; st >>= 1) {
        if (tid < st) red[tid] += red[tid + st];
        __syncthreads();
    }
    double r = red[0];
    __syncthreads();
    return r;
}

__device__ inline unsigned short f2bf(float x) {
    unsigned u = __float_as_uint(x);
    unsigned r = (u + 0x7fffu + ((u >> 16) & 1u)) >> 16;
    return (unsigned short)r;
}

__device__ inline float bf2f(unsigned short b) {
    unsigned u = ((unsigned)b) << 16;
    return __uint_as_float(u);
}

__device__ inline void gload_lds16(const void* g, void* l) {
    __builtin_amdgcn_global_load_lds((const __attribute__((address_space(1))) void*)g,
                                     (__attribute__((address_space(3))) void*)l, 16, 0, 0);
}

// ---------------- K0: norms + bf16 casts (s and normalized t) ----------------

__global__ __launch_bounds__(256) void prep_kernel(
    const float* __restrict__ s, const float* __restrict__ t,
    unsigned short* __restrict__ shi, unsigned short* __restrict__ thi,
    float* __restrict__ sn2, float* __restrict__ tn2)
{
    int row = blockIdx.x;
    int tid = threadIdx.x;
    const float* srow = s + (size_t)row * DD;
    const float* trow = t + (size_t)row * DD;
    float s0 = srow[tid], s1 = srow[tid + 256];
    float t0 = trow[tid], t1 = trow[tid + 256];
    __shared__ float red[256];
    float ssum = block_reduce_sum_f(s0 * s0 + s1 * s1, red);
    float tsum = block_reduce_sum_f(t0 * t0 + t1 * t1, red);
    float nrm = fmaxf(sqrtf(tsum), 1e-12f);
    float u0 = t0 / nrm, u1 = t1 / nrm;
    float usum = block_reduce_sum_f(u0 * u0 + u1 * u1, red);
    shi[(size_t)row * DD + tid] = f2bf(s0);
    shi[(size_t)row * DD + tid + 256] = f2bf(s1);
    thi[(size_t)row * DD + tid] = f2bf(u0);
    thi[(size_t)row * DD + tid + 256] = f2bf(u1);
    if (tid == 0) {
        sn2[row] = ssum;
        tn2[row] = usum;
    }
}

// ---------------- K1: fused symmetric 1-pass bf16 MFMA Gram ----------------
// blocks [0, ntri)      : S gram -> Sb = sqrt(max(d2,0))
// blocks [ntri, 2*ntri) : T gram -> Wb = exp(-max(d2,0))

#define BM 128
#define BK 32

__global__ __launch_bounds__(256) void gram_fused_kernel(
    const unsigned short* __restrict__ shi, const unsigned short* __restrict__ thi,
    const float* __restrict__ sn2, const float* __restrict__ tn2,
    unsigned short* __restrict__ Sb, unsigned short* __restrict__ Wb, int ntri)
{
    __shared__ unsigned short lsA[BM * BK];
    __shared__ unsigned short lsB[BM * BK];

    int bid = blockIdx.x;
    bool isS = (bid < ntri);
    int q = isS ? bid : bid - ntri;
    const unsigned short* Xhi = isS ? shi : thi;
    const float* xsq = isS ? sn2 : tn2;
    unsigned short* out = isS ? Sb : Wb;

    // triangular decode: q -> (bi, bj), bi <= bj
    int bi = 0;
    while (q >= (NN / BM - bi)) { q -= (NN / BM - bi); ++bi; }
    int bj = bi + q;
    int i0 = bi * BM, j0 = bj * BM;

    int t = threadIdx.x;
    int wave = t >> 6, lane = t & 63;
    int wr = wave >> 1, wc = wave & 1;

    f32x4 acc[4][4] = {};

    int srow = t >> 2;                       // 0..63 (row within 64-row half)
    int slot = t & 3;                        // LDS 16B slot within row
    int ksrc = slot ^ ((srow >> 1) & 3);     // pre-swizzled global column chunk
    int scol = ksrc * 8;

    for (int k0 = 0; k0 < DD; k0 += BK) {
#pragma unroll
        for (int p = 0; p < 2; ++p) {
            size_t ga = (size_t)(i0 + p * 64 + srow) * DD + k0 + scol;
            size_t gb = (size_t)(j0 + p * 64 + srow) * DD + k0 + scol;
            int lofs = p * 2048 + t * 8;
            gload_lds16(Xhi + ga, &lsA[lofs]);
            gload_lds16(Xhi + gb, &lsB[lofs]);
        }
        __syncthreads();

        int fr = lane & 15, kg = lane >> 4;
        bf16x8 ah[4], bh[4];
#pragma unroll
        for (int m = 0; m < 4; ++m) {
            int row = wr * 64 + m * 16 + fr;
            int sofs = row * BK + ((kg ^ ((row >> 1) & 3)) << 3);
            ah[m] = *(const bf16x8*)&lsA[sofs];
        }
#pragma unroll
        for (int n = 0; n < 4; ++n) {
            int row = wc * 64 + n * 16 + fr;
            int sofs = row * BK + ((kg ^ ((row >> 1) & 3)) << 3);
            bh[n] = *(const bf16x8*)&lsB[sofs];
        }
#pragma unroll
        for (int m = 0; m < 4; ++m)
#pragma unroll
            for (int n = 0; n < 4; ++n)
                acc[m][n] = __builtin_amdgcn_mfma_f32_16x16x32_bf16(ah[m], bh[n], acc[m][n], 0, 0, 0);
        __syncthreads();
    }

    // epilogue: C/D layout col = lane&15, row = (lane>>4)*4 + reg
    int fr = lane & 15, fq = lane >> 4;
    float xj[4];
#pragma unroll
    for (int n = 0; n < 4; ++n) xj[n] = xsq[j0 + wc * 64 + n * 16 + fr];
    bool mirror = (bi != bj);
#pragma unroll
    for (int m = 0; m < 4; ++m) {
        int ibase = i0 + wr * 64 + m * 16 + fq * 4;
        float xi[4];
#pragma unroll
        for (int r = 0; r < 4; ++r) xi[r] = xsq[ibase + r];
#pragma unroll
        for (int n = 0; n < 4; ++n) {
            int j = j0 + wc * 64 + n * 16 + fr;
            unsigned short pk[4];
#pragma unroll
            for (int r = 0; r < 4; ++r) {
                float d2 = xi[r] + xj[n] - 2.0f * acc[m][n][r];
                d2 = fmaxf(d2, 0.0f);
                float v = isS ? sqrtf(d2) : expf(-d2);
                pk[r] = f2bf(v);
                out[(size_t)(ibase + r) * NN + j] = pk[r];
            }
            if (mirror) {
                ushort4 u4;
                u4.x = pk[0]; u4.y = pk[1]; u4.z = pk[2]; u4.w = pk[3];
                *(ushort4*)&out[(size_t)j * NN + ibase] = u4;
            }
        }
    }
}

// ---------------- K2: row mean (bf16 input) -> inverse mean ----------------

__global__ __launch_bounds__(256) void rowmean_kernel(
    const unsigned short* __restrict__ Sb, float* __restrict__ invm)
{
    int row = blockIdx.x, tid = threadIdx.x;
    const ushort8v* p = (const ushort8v*)(Sb + (size_t)row * NN);
    float acc = 0.f;
#pragma unroll
    for (int q = 0; q < 2; ++q) {
        ushort8v v = p[tid + 256 * q];
        float a = 0.f;
#pragma unroll
        for (int c = 0; c < 8; ++c) a += bf2f(v[c]);
        acc += a;
    }
    __shared__ float red[256];
    float total = block_reduce_sum_f(acc, red);
    if (tid == 0) {
        float mean = total / (float)NN;
        invm[row] = 1.0f / mean;
    }
}

// ---------------- K3: per-row stable top-10 via packed u32 keys ----------------
// key = (bf16_bits << 16) | (4095 - j): descending value, ascending index.

__global__ __launch_bounds__(256) void topk_kernel(
    const unsigned short* __restrict__ Wb, const int* __restrict__ idx, int* __restrict__ topk)
{
    __shared__ unsigned mk[256 * K_TOP];
    int row = blockIdx.x, tid = threadIdx.x;
    int myidx = idx[row];
    const ushort8v* w8 = (const ushort8v*)(Wb + (size_t)row * NN);
    const int4* i4 = (const int4*)idx;

    unsigned v[K_TOP];
#pragma unroll
    for (int p = 0; p < K_TOP; ++p) v[p] = 0u;

#pragma unroll
    for (int q = 0; q < 2; ++q) {
        int j8 = tid + 256 * q;
        ushort8v wv = w8[j8];
        int4 ia = i4[j8 * 2];
        int4 ib = i4[j8 * 2 + 1];
        int ii[8] = {ia.x, ia.y, ia.z, ia.w, ib.x, ib.y, ib.z, ib.w};
#pragma unroll
        for (int c = 0; c < 8; ++c) {
            int j = j8 * 8 + c;
            unsigned val = (ii[c] == myidx) ? 0x3F80u : (unsigned)(unsigned short)wv[c];
            unsigned nk = (val << 16) | (unsigned)(4095 - j);
#pragma unroll
            for (int p = K_TOP - 1; p >= 1; --p) {
                if (nk > v[p - 1]) v[p] = v[p - 1];
                else if (nk > v[p]) v[p] = nk;
            }
            if (nk > v[0]) v[0] = nk;
        }
    }

#pragma unroll
    for (int p = 0; p < K_TOP; ++p) mk[tid * K_TOP + p] = v[p];
    __syncthreads();

    for (int stride = 128; stride >= 1; stride >>= 1) {
        if (tid < stride) {
            int a = tid * K_TOP, b = (tid + stride) * K_TOP;
            unsigned ov[K_TOP];
            int pa = 0, pb = 0;
#pragma unroll
            for (int p = 0; p < K_TOP; ++p) {
                unsigned va = mk[a + pa], vb = mk[b + pb];
                bool ta = (va > vb);
                ov[p] = ta ? va : vb;
                pa += ta ? 1 : 0;
                pb += ta ? 0 : 1;
            }
#pragma unroll
            for (int p = 0; p < K_TOP; ++p) mk[a + p] = ov[p];
        }
        __syncthreads();
    }

    if (tid == 0) {
#pragma unroll
        for (int p = 0; p < K_TOP; ++p)
            topk[row * K_TOP + p] = 4095 - (int)(mk[p] & 0xFFFFu);
    }
}

// ---------------- K4: mutual-NN lists (V) ----------------

__global__ __launch_bounds__(256) void mutual_kernel(
    const int* __restrict__ topk, int* __restrict__ vnbr, int* __restrict__ vcnt)
{
    int i = blockIdx.x * 256 + threadIdx.x;
    if (i >= NN) return;
    int mine[K_TOP];
#pragma unroll
    for (int a = 0; a < K_TOP; ++a) mine[a] = topk[i * K_TOP + a];
    int cnt = 0;
    int out[K_TOP];
#pragma unroll
    for (int a = 0; a < K_TOP; ++a) {
        int j = mine[a];
        bool found = false;
#pragma unroll
        for (int b = 0; b < K_TOP; ++b) found |= (topk[j * K_TOP + b] == i);
        if (found) out[cnt++] = j;
    }
    vcnt[i] = cnt;
    for (int a = 0; a < cnt; ++a) vnbr[i * K_TOP + a] = out[a];
    for (int a = cnt; a < K_TOP; ++a) vnbr[i * K_TOP + a] = -1;
}

// ---------------- K5: W_C_tilda values (co/deg) ----------------

__global__ __launch_bounds__(256) void wct_kernel(
    const int* __restrict__ vnbr, const int* __restrict__ vcnt, float* __restrict__ wct)
{
    int i = blockIdx.x * 256 + threadIdx.x;
    if (i >= NN) return;
    int cnt = vcnt[i];
    int mine[K_TOP];
#pragma unroll
    for (int a = 0; a < K_TOP; ++a) mine[a] = vnbr[i * K_TOP + a];
    float invdeg = 1.0f / fmaxf((float)cnt, 1.0f);
    for (int a = 0; a < K_TOP; ++a) {
        if (a < cnt) {
            int j = mine[a];
            int cj = vcnt[j];
            int co = 0;
            for (int b = 0; b < cj; ++b) {
                int v = vnbr[j * K_TOP + b];
#pragma unroll
                for (int c = 0; c < K_TOP; ++c)
                    co += (c < cnt && mine[c] == v) ? 1 : 0;
            }
            wct[i * K_TOP + a] = (float)co * invdeg;
        } else {
            wct[i * K_TOP + a] = 0.0f;
        }
    }
}

// ---------------- K6: sparse W_C correction ----------------

__global__ __launch_bounds__(256) void corr_kernel(
    const int* __restrict__ topk, const int* __restrict__ vnbr, const int* __restrict__ vcnt,
    const float* __restrict__ wct, const unsigned short* __restrict__ Sb,
    const float* __restrict__ invm, double* __restrict__ partial)
{
    int r = blockIdx.x * 256 + threadIdx.x;
    double acc = 0.0;
    if (r < NN) {
        float im_r = invm[r];
        for (int a = 0; a < K_HALF; ++a) {
            int k = topk[r * K_TOP + a];
            int ck = vcnt[k];
            for (int b = 0; b < ck; ++b) {
                int c = vnbr[k * K_TOP + b];
                if (c == r) continue;
                float w = wct[k * K_TOP + b];
                float sr = bf2f(Sb[(size_t)r * NN + c]);
                float s1 = sr * im_r;
                float r1 = fmaxf(1.0f - s1, 0.0f);
                float g1 = s1 * s1 - r1 * r1;
                float s2 = sr * invm[c];
                float r2 = fmaxf(1.0f - s2, 0.0f);
                float g2 = s2 * s2 - r2 * r2;
                acc += (double)(w * (g1 + g2)) * (1.0 / 20.0);
            }
        }
    }
    __shared__ double red[256];
    double total = block_reduce_sum_d(acc, red);
    if (threadIdx.x == 0) partial[blockIdx.x] = total;
}

// ---------------- K7: dense loss part (bf16 inputs) ----------------

__global__ __launch_bounds__(256) void dense_kernel(
    const unsigned short* __restrict__ Sb, const unsigned short* __restrict__ Wb,
    const float* __restrict__ invm, double* __restrict__ partial)
{
    int row = blockIdx.x, tid = threadIdx.x;
    const ushort8v* S8 = (const ushort8v*)(Sb + (size_t)row * NN);
    const ushort8v* W8 = (const ushort8v*)(Wb + (size_t)row * NN);
    float im = invm[row];
    double acc = 0.0;
#pragma unroll
    for (int q = 0; q < 2; ++q) {
        int j8 = tid + 256 * q;
        ushort8v sv = S8[j8];
        ushort8v wv = W8[j8];
        float part = 0.f;
        bool hasdiag = (j8 * 8 <= row) && (row < j8 * 8 + 8);
#pragma unroll
        for (int c = 0; c < 8; ++c) {
            float sc = bf2f(sv[c]) * im;
            float rr = fmaxf(1.0f - sc, 0.0f);
            float term = rr * rr + 0.5f * bf2f(wv[c]) * (sc * sc - rr * rr);
            part += term;
        }
        if (hasdiag) {
            int c = row - j8 * 8;
            float sc = bf2f(sv[c]) * im;
            float rr = fmaxf(1.0f - sc, 0.0f);
            part -= rr * rr + 0.5f * bf2f(wv[c]) * (sc * sc - rr * rr);
        }
        acc += (double)part;
    }
    __shared__ double red[256];
    double total = block_reduce_sum_d(acc, red);
    if (tid == 0) partial[row] = total;
}

// ---------------- K8: final reduce ----------------

__global__ __launch_bounds__(256) void final_kernel(
    const double* __restrict__ pDense, const double* __restrict__ pCorr, float* __restrict__ out)
{
    int tid = threadIdx.x;
    double a = 0.0;
    for (int j = tid; j < NN; j += 256) a += pDense[j];
    if (tid < 16) a += pCorr[tid];
    __shared__ double red[256];
    double total = block_reduce_sum_d(a, red);
    if (tid == 0) out[0] = (float)(total / ((double)NN * (double)(NN - 1)));
}

// ---------------- launcher ----------------

extern "C" void kernel_launch(void* const* d_in, const int* in_sizes, int n_in,
                              void* d_out, int out_size, void* d_ws, size_t ws_size,
                              hipStream_t stream)
{
    const float* s = (const float*)d_in[0];
    const float* t = (const float*)d_in[1];
    const int* idx = (const int*)d_in[2];
    float* out = (float*)d_out;

    char* base = (char*)d_ws;
    size_t off = 0;
    auto alloc = [&](size_t bytes) -> void* {
        void* p = base + off;
        off = (off + bytes + 511) & ~(size_t)511;
        return p;
    };

    unsigned short* Sb = (unsigned short*)alloc((size_t)NN * NN * 2);
    unsigned short* Wb = (unsigned short*)alloc((size_t)NN * NN * 2);
    unsigned short* shi = (unsigned short*)alloc((size_t)NN * DD * 2);
    unsigned short* thi = (unsigned short*)alloc((size_t)NN * DD * 2);
    float* sn2  = (float*)alloc(NN * 4);
    float* tn2  = (float*)alloc(NN * 4);
    float* invm = (float*)alloc(NN * 4);
    int* topk   = (int*)alloc(NN * K_TOP * 4);
    int* vnbr   = (int*)alloc(NN * K_TOP * 4);
    int* vcnt   = (int*)alloc(NN * 4);
    float* wct  = (float*)alloc(NN * K_TOP * 4);
    double* pDense = (double*)alloc(NN * 8);
    double* pCorr  = (double*)alloc(16 * 8);
    (void)ws_size;

    int ntile = NN / BM;
    int ntri = ntile * (ntile + 1) / 2;

    prep_kernel<<<NN, 256, 0, stream>>>(s, t, shi, thi, sn2, tn2);
    gram_fused_kernel<<<2 * ntri, 256, 0, stream>>>(shi, thi, sn2, tn2, Sb, Wb, ntri);

    rowmean_kernel<<<NN, 256, 0, stream>>>(Sb, invm);
    topk_kernel<<<NN, 256, 0, stream>>>(Wb, idx, topk);
    mutual_kernel<<<NN / 256, 256, 0, stream>>>(topk, vnbr, vcnt);
    wct_kernel<<<NN / 256, 256, 0, stream>>>(vnbr, vcnt, wct);
    corr_kernel<<<NN / 256, 256, 0, stream>>>(topk, vnbr, vcnt, wct, Sb, invm, pCorr);
    dense_kernel<<<NN, 256, 0, stream>>>(Sb, Wb, invm, pDense);
    final_kernel<<<1, 256, 0, stream>>>(pDense, pCorr, out);
}